// Round 6
// baseline (3929.811 us; speedup 1.0000x reference)
//
#include <hip/hip_runtime.h>
#include <stdint.h>
#include <math.h>

typedef unsigned long long u64;
typedef unsigned int u32;
typedef _Float16 half8 __attribute__((ext_vector_type(8)));
typedef float f32x4 __attribute__((ext_vector_type(4)));
typedef float float8 __attribute__((ext_vector_type(8)));

#define CC   512
#define HH   50
#define WW2  76
#define PP   3800      // HH*WW2
#define NB   8
#define NA   34200     // PP*9
#define PRE  6000
#define POST 300
#define MWORDS 96      // u64 words per mask row (94 used, padded)
#define NPAD 8192      // bitonic sort size
#define SCHUNK 1069    // float4-chunks per select block (8 blocks x 1069 >= 8550)

// ---------------- workspace layout (bytes) ----------------
// wh2   @ 0            65,536      (64 x 512 f16)
// wl2   @ 65,536       65,536
// whF   @ 131,072      4,718,592   (frag-major conv weights hi)
// wlF   @ 4,849,664    4,718,592   -> end 9,568,256
// xh    @ 9,568,256    15,564,800  (4 img x 3800 x 512 f16, per-batch)
// xl    @ 25,133,056   15,564,800  -> end 40,697,856
// p0    @ 40,697,856   31,129,600  (K-half-0 partial, f32, 4 img)
// p1    @ 71,827,456   31,129,600  -> end 102,957,056
// boxes @ 102,957,056  4,377,600
// scores@ 107,334,656  1,094,400
// sb    @ 108,429,056    192,000
// bbs   @ 108,621,056    768,000
// areas @ 109,389,056    192,000
// selst @ 109,581,056     16,384   (ghist 8192 | gccnt | gpref | grem) - outside all overlays
// arr   @ 109,597,440    524,288   (NB x 8192 u64)
// mask  @ 40,697,856   36,864,000  (overlays p0/p1 after hgemm done)
// peak 110.1 MB (<= 115.7 MB proven safe)

__device__ __forceinline__ u32 skey(float f) {
    u32 u = __float_as_uint(f);
    return (u & 0x80000000u) ? ~u : (u | 0x80000000u);
}

__device__ __forceinline__ float4 anchor_at(int p, int a) {
    const float rv[3] = {0.5f, 1.0f, 2.0f};
    const float sv[3] = {8.0f, 16.0f, 32.0f};
    int ri = a / 3, si = a % 3;
    float s16 = 16.0f * sv[si];
    float hh = s16 * sqrtf(rv[ri]);
    float ww = s16 * sqrtf(1.0f / rv[ri]);
    float bx1 = 8.0f - 0.5f * ww, by1 = 8.0f - 0.5f * hh;
    float bx2 = 8.0f + 0.5f * ww, by2 = 8.0f + 0.5f * hh;
    float sx = (float)((p % WW2) * 16);
    float sy = (float)((p / WW2) * 16);
    return make_float4(sx + bx1, sy + by1, sx + bx2, sy + by2);
}

// LDS slot swizzle for A staging: octet j of row m
__device__ __forceinline__ int lds_slot(int m, int j) {
    return (((m >> 4) * 64) + ((m & 15) ^ ((4 * (j & 1)) | (8 * (j >> 1)))) + (j << 4)) << 3;
}

// ---------------- kernel: split x into f16 hi/lo, transposed [p][c] --------------
// grid (119, 16, 4), block (32,8)
__global__ void k_split_x(const float* __restrict__ x, _Float16* __restrict__ xh,
                          _Float16* __restrict__ xl) {
    __shared__ float S[32][33];
    int zim = blockIdx.z;
    int p0 = blockIdx.x * 32, c0 = blockIdx.y * 32;
    int tx = threadIdx.x, ty0 = threadIdx.y;
    const float* xi = x + (size_t)zim * CC * PP;
#pragma unroll
    for (int yy = 0; yy < 32; yy += 8) {
        int cty = c0 + ty0 + yy, ptx = p0 + tx;
        S[ty0 + yy][tx] = (ptx < PP) ? xi[(size_t)cty * PP + ptx] : 0.f;
    }
    __syncthreads();
#pragma unroll
    for (int yy = 0; yy < 32; yy += 8) {
        int p = p0 + ty0 + yy;
        if (p < PP) {
            float v = S[tx][ty0 + yy];
            _Float16 h = (_Float16)v;
            float r = v - (float)h;
            size_t o = (size_t)(zim * PP + p) * 512 + c0 + tx;
            xh[o] = h;
            xl[o] = (_Float16)(r * 2048.0f);
        }
    }
}

// ---------------- kernel: split conv1 weights -> MFMA frag-major hi/lo -----------
__global__ void k_split_w(const float* __restrict__ w, _Float16* __restrict__ wh,
                          _Float16* __restrict__ wl) {
    __shared__ float S[4608];
    int co = blockIdx.x;
    for (int t = threadIdx.x; t < 4608; t += 256) S[t] = w[(size_t)co * 4608 + t];
    __syncthreads();
    int g = co >> 4, nlo = co & 15;
    for (int e = threadIdx.x; e < 4608; e += 256) {
        int cc = e / 9, idx = e - cc * 9;
        float v = S[cc * 9 + idx];
        _Float16 h = (_Float16)v;
        float r = v - (float)h;
        int kk = (cc >> 5) * 9 + idx;
        int lane = ((cc >> 3) & 3) * 16 + nlo;
        int j = cc & 7;
        size_t d = (((size_t)g * 144 + kk) * 64 + lane) * 8 + j;
        wh[d] = h;
        wl[d] = (_Float16)(r * 2048.0f);
    }
}

// ---------------- kernel: split head weights into [64][512] f16 hi/lo -----------
__global__ void k_split_w2(const float* __restrict__ lw, const float* __restrict__ sw,
                           _Float16* __restrict__ wh2, _Float16* __restrict__ wl2) {
    int row = blockIdx.x, k = threadIdx.x;
    float v = (row < 36) ? lw[row * 512 + k] : (row < 54 ? sw[(row - 36) * 512 + k] : 0.f);
    _Float16 h = (_Float16)v;
    float r = v - (float)h;
    wh2[row * 512 + k] = h;
    wl2[row * 512 + k] = (_Float16)(r * 2048.0f);
}

// ---------------- kernel: 3x3 conv, K-SPLIT split-f16 MFMA implicit GEMM ---------
// Grid 960 (2 K-halves x 480, XCD-pinned), block 256 (4 waves, 2x2), BM=BN=128.
// Each block reduces one K-half (72 of 144 BK=32 chunks) and writes a raw f32
// partial (p0 or p1).  Same per-chunk stage:compute ratio as the 480-block
// version, same total A/B bytes (K-halves are disjoint), but ~2x blocks/CU for
// latency hiding.  relu/bias/f16-split move to the consumer (k_hgemm_post).
__global__ __launch_bounds__(256, 3) void k_conv(
    const _Float16* __restrict__ xh, const _Float16* __restrict__ xl,
    const _Float16* __restrict__ whF, const _Float16* __restrict__ wlF,
    float* __restrict__ p0v, float* __restrict__ p1v)
{
    __shared__ _Float16 lds[2 * 8192];
    const int tid = threadIdx.x;
    const int L = blockIdx.x;
    const int X = L & 7, q = L >> 3;          // q in 0..119
    const int kh = (q >= 60) ? 1 : 0;
    const int q2 = q - kh * 60;               // 0..59
    const int nt = X & 3;
    const int zim = (X >> 2) * 2 + (q2 >= 30 ? 1 : 0);
    const int mt = q2 - (q2 >= 30 ? 30 : 0);
    const int m0 = mt * 128, n0 = nt * 128;
    const _Float16* xhi = xh + (size_t)zim * CC * PP;
    const _Float16* xlo = xl + (size_t)zim * CC * PP;

    const int mA0 = tid >> 2, jA0 = tid & 3;
    const int mA1 = 64 + (tid >> 2);

    f32x4 acc[4][4], acc2[4][4];
#pragma unroll
    for (int i = 0; i < 4; ++i)
#pragma unroll
        for (int j = 0; j < 4; ++j) {
            acc[i][j] = f32x4{0.f, 0.f, 0.f, 0.f};
            acc2[i][j] = f32x4{0.f, 0.f, 0.f, 0.f};
        }

    uint4 pa0h, pa0l, pa1h, pa1l;

    auto ld_a = [&](int m, int idx, int c0, uint4& vh, uint4& vl) {
        int dy = idx / 3 - 1, dx = idx % 3 - 1;
        int p = m0 + m;
        int px = p % 76, py = p / 76;
        bool av = (p < PP) && ((unsigned)(py + dy) < 50u) && ((unsigned)(px + dx) < 76u);
        if (av) {
            size_t off = (size_t)(p + dy * 76 + dx) * 512 + c0 + jA0 * 8;
            vh = *(const uint4*)(xhi + off);
            vl = *(const uint4*)(xlo + off);
        } else {
            vh = make_uint4(0, 0, 0, 0);
            vl = make_uint4(0, 0, 0, 0);
        }
    };
    auto stage_load = [&](int kk) {
        int c9 = kk / 9;
        int idx = kk - c9 * 9;
        int c0 = c9 << 5;
        ld_a(mA0, idx, c0, pa0h, pa0l);
        ld_a(mA1, idx, c0, pa1h, pa1l);
    };
    const int sl0 = lds_slot(mA0, jA0);
    const int sl1 = lds_slot(mA1, jA0);
    auto stage_write = [&](int buf) {
        _Float16* Lp = lds + buf * 8192;
        *(uint4*)(Lp + sl0)        = pa0h;
        *(uint4*)(Lp + 4096 + sl0) = pa0l;
        *(uint4*)(Lp + sl1)        = pa1h;
        *(uint4*)(Lp + 4096 + sl1) = pa1l;
    };

    const int lane = tid & 63, wave = tid >> 6;
    const int wm = wave & 1, wn = wave >> 1;
    const int jr = lane >> 4;
    const int rd_off = (((lane & 15) ^ ((4 * (jr & 1)) | (8 * (jr >> 1)))) + (jr << 4)) << 3;
    const int g0 = nt * 8 + wn * 4;
    const size_t lane8 = (size_t)lane * 8;

    half8 b0h[4], b0l[4], b1h[4], b1l[4];
    auto load_b = [&](int kk, half8* bh_, half8* bl_) {
#pragma unroll
        for (int ni = 0; ni < 4; ++ni) {
            size_t off = (((size_t)(g0 + ni) * 144 + kk) * 64) * 8 + lane8;
            bh_[ni] = *(const half8*)(whF + off);
            bl_[ni] = *(const half8*)(wlF + off);
        }
    };

    auto compute = [&](int buf, const half8* bh, const half8* bl) {
        const _Float16* Lp = lds + buf * 8192;
        half8 ah[4], al[4];
#pragma unroll
        for (int mi = 0; mi < 4; ++mi) {
            int slot = (((wm * 4 + mi) * 64) << 3) + rd_off;
            ah[mi] = *(const half8*)(Lp + slot);
            al[mi] = *(const half8*)(Lp + 4096 + slot);
        }
#pragma unroll
        for (int ni = 0; ni < 4; ++ni) {
#pragma unroll
            for (int mi = 0; mi < 4; ++mi) {
                acc[mi][ni]  = __builtin_amdgcn_mfma_f32_16x16x32_f16(ah[mi], bh[ni], acc[mi][ni], 0, 0, 0);
                acc2[mi][ni] = __builtin_amdgcn_mfma_f32_16x16x32_f16(ah[mi], bl[ni], acc2[mi][ni], 0, 0, 0);
                acc2[mi][ni] = __builtin_amdgcn_mfma_f32_16x16x32_f16(al[mi], bh[ni], acc2[mi][ni], 0, 0, 0);
            }
        }
    };

    const int kbase = kh * 72, kend = kbase + 72;
    stage_load(kbase);
    stage_write(0);
    load_b(kbase, b0h, b0l);
    __syncthreads();
    for (int kk = kbase; kk < kend; kk += 2) {
        stage_load(kk + 1);
        load_b(kk + 1, b1h, b1l);
        compute(0, b0h, b0l);
        stage_write(1);
        __syncthreads();
        if (kk + 2 < kend) {
            stage_load(kk + 2);
            load_b(kk + 2, b0h, b0l);
        }
        compute(1, b1h, b1l);
        if (kk + 2 < kend) stage_write(0);
        __syncthreads();
    }

    float* P = kh ? p1v : p0v;
    const int qq = lane >> 4, cl = lane & 15;
    const size_t rowbase = (size_t)zim * PP;
#pragma unroll
    for (int ni = 0; ni < 4; ++ni) {
        int n = n0 + (wn * 4 + ni) * 16 + cl;
#pragma unroll
        for (int mi = 0; mi < 4; ++mi) {
            int mb = m0 + (wm * 4 + mi) * 16 + qq * 4;
            if (mb < PP) {
#pragma unroll
                for (int r = 0; r < 4; ++r)
                    P[(rowbase + mb + r) * 512 + n] =
                        acc[mi][ni][r] + acc2[mi][ni][r] * (1.f / 2048.f);
            }
        }
    }
}

// ---------------- kernel: head GEMM + fused decode, K-split partial combine ------
// A = relu(p0 + p1 + conv_bias) reconstructed in registers and split to f16 hi/lo.
// Per-batch (4 images); grid (60, 4).
__global__ __launch_bounds__(256) void k_hgemm_post(
    const float* __restrict__ p0v, const float* __restrict__ p1v,
    const float* __restrict__ cbias,
    const _Float16* __restrict__ wh2, const _Float16* __restrict__ wl2,
    const float* __restrict__ lb, const float* __restrict__ sbias,
    const int* __restrict__ imh_p, const int* __restrict__ imw_p,
    float* __restrict__ out0, float* __restrict__ out1,
    float* __restrict__ boxes, float* __restrict__ scores,
    float* __restrict__ out3, int imgbase)
{
    const int img_l = blockIdx.y;
    const int img = imgbase + img_l;
    const int prow0 = blockIdx.x * 64;
    const int wave = threadIdx.x >> 6, lane = threadIdx.x & 63;
    const int q8 = (lane >> 4) * 8;
    int arow = img_l * PP + prow0 + wave * 16 + (lane & 15);
    if (arow >= 4 * PP) arow = 4 * PP - 1;
    const float* a0 = p0v + (size_t)arow * 512 + q8;
    const float* a1 = p1v + (size_t)arow * 512 + q8;
    const _Float16* bhp = wh2 + (size_t)(lane & 15) * 512 + q8;
    const _Float16* blp = wl2 + (size_t)(lane & 15) * 512 + q8;

    f32x4 acc[4], acc2[4];
#pragma unroll
    for (int j = 0; j < 4; ++j) {
        acc[j] = f32x4{0.f, 0.f, 0.f, 0.f};
        acc2[j] = f32x4{0.f, 0.f, 0.f, 0.f};
    }

#pragma unroll 4
    for (int k0 = 0; k0 < 512; k0 += 32) {
        float8 v0 = *(const float8*)(a0 + k0);
        float8 v1 = *(const float8*)(a1 + k0);
        float8 bv = *(const float8*)(cbias + q8 + k0);
        half8 ah, al;
#pragma unroll
        for (int j = 0; j < 8; ++j) {
            float fv = fmaxf(v0[j] + v1[j] + bv[j], 0.f);
            _Float16 h = (_Float16)fv;
            ah[j] = h;
            al[j] = (_Float16)((fv - (float)h) * 2048.0f);
        }
#pragma unroll
        for (int nf = 0; nf < 4; ++nf) {
            half8 bh = *(const half8*)(bhp + (size_t)nf * 16 * 512 + k0);
            half8 bl = *(const half8*)(blp + (size_t)nf * 16 * 512 + k0);
            acc[nf]  = __builtin_amdgcn_mfma_f32_16x16x32_f16(ah, bh, acc[nf], 0, 0, 0);
            acc2[nf] = __builtin_amdgcn_mfma_f32_16x16x32_f16(ah, bl, acc2[nf], 0, 0, 0);
            acc2[nf] = __builtin_amdgcn_mfma_f32_16x16x32_f16(al, bh, acc2[nf], 0, 0, 0);
        }
    }

    // stage the 64x64 O tile to LDS
    __shared__ float Ls[64][68];
    const int q = lane >> 4, cl = lane & 15;
#pragma unroll
    for (int nf = 0; nf < 4; ++nf) {
        int n = nf * 16 + cl;
        float bs = (n < 36) ? lb[n] : (n < 54 ? sbias[n - 36] : 0.f);
#pragma unroll
        for (int r = 0; r < 4; ++r) {
            int ml = wave * 16 + q * 4 + r;
            Ls[ml][n] = acc[nf][r] + acc2[nf][r] * (1.f / 2048.f) + bs;
        }
    }
    __syncthreads();

    // decode: 64 rows x 9 anchors = 576 tasks over 256 threads
    const float fimh = (float)(*imh_p), fimw = (float)(*imw_p);
    for (int task = threadIdx.x; task < 576; task += 256) {
        int pl = task / 9, a = task - pl * 9;
        int p = prow0 + pl;
        if (p >= PP) continue;
        float4 loc = *(const float4*)&Ls[pl][a * 4];
        float2 sc = make_float2(Ls[pl][36 + a * 2], Ls[pl][36 + a * 2 + 1]);
        size_t ai = (size_t)img * NA + (size_t)p * 9 + a;
        *(float4*)&out0[ai * 4] = loc;
        *(float2*)&out1[ai * 2] = sc;
        float mx = fmaxf(sc.x, sc.y);
        float e0 = expf(sc.x - mx), e1 = expf(sc.y - mx);
        float fg = e1 / (e0 + e1);
        float4 an = anchor_at(p, a);
        if (img == 0) ((float4*)out3)[p * 9 + a] = an;
        float aw = an.z - an.x, ah2 = an.w - an.y;
        float ax = an.x + 0.5f * aw, ay = an.y + 0.5f * ah2;
        float cx = loc.x * aw + ax;
        float cy = loc.y * ah2 + ay;
        float wb = expf(loc.z) * aw, hb = expf(loc.w) * ah2;
        float x1 = cx - 0.5f * wb, y1 = cy - 0.5f * hb;
        float x2 = cx + 0.5f * wb, y2 = cy + 0.5f * hb;
        x1 = fminf(fmaxf(x1, 0.f), fimw);
        x2 = fminf(fmaxf(x2, 0.f), fimw);
        y1 = fminf(fmaxf(y1, 0.f), fimh);
        y2 = fminf(fmaxf(y2, 0.f), fimh);
        bool valid = ((x2 - x1) >= 16.0f) && ((y2 - y1) >= 16.0f);
        ((float4*)boxes)[ai] = make_float4(x1, y1, x2, y2);
        scores[ai] = valid ? fg : -INFINITY;
    }
}

// ================= selection pipeline ============================================

// ---- histogram pass: per-wave privatized LDS hist -> global atomics -------------
__global__ __launch_bounds__(256) void k_sel_hist(
    const float* __restrict__ scores, u32* __restrict__ ghist,
    const u32* __restrict__ gpref, int sh, int pass)
{
    __shared__ u32 wh[4][256];
    const int img = blockIdx.y, blk = blockIdx.x;
    const int tid = threadIdx.x, wv = tid >> 6;
#pragma unroll
    for (int w = 0; w < 4; ++w) wh[w][tid] = 0;
    __syncthreads();
    const u32 pmask = (pass == 0) ? 0u : (0xFFFFFFFFu << (sh + 8));
    const u32 pref = (pass == 0) ? 0u : gpref[img];
    const float4* sc4 = (const float4*)(scores + (size_t)img * NA);
    const int e40 = blk * SCHUNK;
    const int e41 = min(e40 + SCHUNK, NA / 4);
    for (int e4 = e40 + tid; e4 < e41; e4 += 256) {
        float4 s4 = sc4[e4];
        u32 kv[4] = {skey(s4.x), skey(s4.y), skey(s4.z), skey(s4.w)};
#pragma unroll
        for (int v = 0; v < 4; ++v)
            if ((kv[v] & pmask) == pref) atomicAdd(&wh[wv][(kv[v] >> sh) & 255u], 1u);
    }
    __syncthreads();
    u32 s = wh[0][tid] + wh[1][tid] + wh[2][tid] + wh[3][tid];
    if (s) atomicAdd(&ghist[img * 256 + tid], s);
}

// ---- scan pass: suffix-sum over 256 bins, pick digit, update pref/rem, re-zero --
__global__ __launch_bounds__(256) void k_sel_scan(
    u32* __restrict__ ghist, u32* __restrict__ gpref, u32* __restrict__ grem,
    int sh, int pass)
{
    __shared__ u32 A[256];
    __shared__ int s_d;
    const int img = blockIdx.x, t = threadIdx.x;
    u32 h = ghist[img * 256 + t];
    A[t] = h;
    if (t == 0) s_d = 0;
    __syncthreads();
    for (int off = 1; off < 256; off <<= 1) {
        u32 v = A[t] + ((t + off < 256) ? A[t + off] : 0u);
        __syncthreads();
        A[t] = v;
        __syncthreads();
    }
    const u32 rem = (pass == 0) ? (u32)PRE : grem[img];
    if (A[t] >= rem) atomicMax(&s_d, t);
    __syncthreads();
    if (t == 0) {
        int d = s_d;
        u32 snext = (d < 255) ? A[d + 1] : 0u;
        u32 pv = (pass == 0) ? 0u : gpref[img];
        gpref[img] = pv | ((u32)d << sh);
        grem[img] = rem - snext;
    }
    ghist[img * 256 + t] = 0;
}

// ---- collect: block-local LDS compaction, one global atomic per block -----------
__global__ __launch_bounds__(256) void k_sel_collect(
    const float* __restrict__ scores, const u32* __restrict__ gpref,
    u32* __restrict__ gccnt, u64* __restrict__ arr)
{
    __shared__ u64 lst[4288];
    __shared__ u32 s_c, s_base;
    const int img = blockIdx.y, blk = blockIdx.x;
    const int tid = threadIdx.x, lane = tid & 63;
    if (tid == 0) s_c = 0;
    __syncthreads();
    const u32 T = gpref[img];
    const float4* sc4 = (const float4*)(scores + (size_t)img * NA);
    const int e40 = blk * SCHUNK;
    const int e41 = min(e40 + SCHUNK, NA / 4);
    for (int e4 = e40 + tid; e4 < e41; e4 += 256) {
        float4 s4 = sc4[e4];
        u32 ks[4] = {skey(s4.x), skey(s4.y), skey(s4.z), skey(s4.w)};
#pragma unroll
        for (int v = 0; v < 4; ++v) {
            bool take = ks[v] >= T;
            u64 bal = __ballot(take);
            if (bal) {
                int leader = __builtin_ctzll(bal);
                u32 base = 0;
                if (lane == leader) base = atomicAdd(&s_c, (u32)__popcll(bal));
                base = (u32)__shfl((int)base, leader);
                if (take)
                    lst[base + (u32)__popcll(bal & ((1ull << lane) - 1ull))] =
                        ((u64)ks[v] << 32) | (u64)(~(u32)(e4 * 4 + v));
            }
        }
    }
    __syncthreads();
    if (tid == 0) s_base = atomicAdd(&gccnt[img], s_c);
    __syncthreads();
    const u32 base = s_base, c = s_c;
    u64* ar = arr + (size_t)img * NPAD;
    for (u32 t = tid; t < c; t += 256) {
        u32 pos = base + t;
        if (pos < NPAD) ar[pos] = lst[t];
    }
}

// ---- sort + output: bitonic over 8192 keys in LDS, gather boxes/areas -----------
__global__ __launch_bounds__(1024) void k_sel_sort(
    const float* __restrict__ scores, const float4* __restrict__ boxes,
    const u64* __restrict__ arr, const u32* __restrict__ gccnt,
    float* __restrict__ sb, float4* __restrict__ bbs, float* __restrict__ areas)
{
    extern __shared__ u64 dyn[];
    u64* a = dyn;
    const int img = blockIdx.x, tid = threadIdx.x;
    u32 n = gccnt[img]; if (n > NPAD) n = NPAD;
    const u64* ar = arr + (size_t)img * NPAD;
    for (int t = tid; t < NPAD; t += 1024) a[t] = ((u32)t < n) ? ar[t] : 0ull;
    for (u32 size = 2; size <= NPAD; size <<= 1) {
        for (u32 stride = size >> 1; stride > 0; stride >>= 1) {
            __syncthreads();
            for (u32 t2 = tid; t2 < NPAD / 2; t2 += 1024) {
                u32 i = 2 * t2 - (t2 & (stride - 1));
                u32 j = i + stride;
                u64 x = a[i], y = a[j];
                bool desc = ((i & size) == 0);
                if (desc ? (x < y) : (x > y)) { a[i] = y; a[j] = x; }
            }
        }
    }
    __syncthreads();
    const float* sc = scores + (size_t)img * NA;
    for (int t2 = tid; t2 < PRE; t2 += 1024) {
        u64 v = a[t2];
        u32 e = ~(u32)v;
        float s = sc[e];
        float4 bx = boxes[(size_t)img * NA + e];
        sb[img * PRE + t2] = s;
        bbs[img * PRE + t2] = bx;
        areas[img * PRE + t2] = (bx.z - bx.x) * (bx.w - bx.y);
    }
}

// ---------------- kernel: IoU suppression bitmask (upper-triangular tiles) -------
__global__ __launch_bounds__(256) void k_mask(
    const float4* __restrict__ bbs, const float* __restrict__ areas,
    u64* __restrict__ mask)
{
    int img = blockIdx.z, iT = blockIdx.x, jT = blockIdx.y;
    if (jT * 256 + 255 <= iT * 64) return;
    int tid = threadIdx.x;
    __shared__ float4 jb[256];
    __shared__ float ja[256];
    int jj = jT * 256 + tid;
    jb[tid] = (jj < PRE) ? bbs[(size_t)img * PRE + jj] : make_float4(0, 0, 0, 0);
    ja[tid] = (jj < PRE) ? areas[img * PRE + jj] : 0.f;
    __syncthreads();
    int i = iT * 64 + (tid & 63);
    int jw = jT * 4 + (tid >> 6);
    if (i >= PRE) return;
    float4 bi = bbs[(size_t)img * PRE + i];
    float ai = areas[img * PRE + i];
    int j0 = (tid >> 6) * 64;
    u64 m = 0;
#pragma unroll 4
    for (int b = 0; b < 64; ++b) {
        int j = jw * 64 + b;
        if (j >= PRE) break;
        if (j > i) {
            float4 bj = jb[j0 + b];
            float xx1 = fmaxf(bi.x, bj.x), yy1 = fmaxf(bi.y, bj.y);
            float xx2 = fminf(bi.z, bj.z), yy2 = fminf(bi.w, bj.w);
            float iw = fmaxf(xx2 - xx1, 0.f), ih2 = fmaxf(yy2 - yy1, 0.f);
            float inter = iw * ih2;
            float iou = inter / (ai + ja[j0 + b] - inter + 1e-9f);
            if (iou > 0.7f) m |= (1ull << b);
        }
    }
    mask[((size_t)img * PRE + i) * MWORDS + jw] = m;
}

// ---------------- kernel: chunked NMS scan — 64 boxes per serial step ------------
__global__ __launch_bounds__(128) void k_scan(
    const float* __restrict__ sb, const float4* __restrict__ bbs,
    const u64* __restrict__ mask, float* __restrict__ out2)
{
    const int img = blockIdx.x;
    const int tid = threadIdx.x;
    const int lane = tid & 63, wv = tid >> 6;
    __shared__ u64 keep[96];
    __shared__ u64 s_keptw;
    __shared__ int list[POST];
    __shared__ int s_n;
    __shared__ int s_kb[64];
    __shared__ int s_kn;

    for (int j0 = 0; j0 < PRE; j0 += 128) {
        int j = j0 + tid;
        bool alive = (j < PRE) && isfinite(sb[(size_t)img * PRE + j]);
        u64 bal = __ballot(alive);
        if (lane == 0) keep[(j0 >> 6) + wv] = bal;
    }
    if (tid == 0) { s_n = 0; keep[94] = 0; keep[95] = 0; }
    __syncthreads();

    const u64* mimg = mask + (size_t)img * PRE * MWORDS;
    for (int w = 0; w < 94; ++w) {
        if (s_n >= POST) break;
        if (wv == 0) {
            u64 myrow = mimg[(size_t)(w * 64 + lane) * MWORDS + w];
            u64 cur = keep[w];
            u64 keptw = 0;
            while (cur) {
                int b = __builtin_ctzll(cur);
                keptw |= 1ull << b;
                u64 row = __shfl(myrow, b);
                u64 hi = (b >= 63) ? 0ull : (~0ull << (b + 1));
                cur &= ~row & hi;
            }
            if (lane == 0) s_keptw = keptw;
        }
        __syncthreads();
        u64 keptw = s_keptw;
        if (tid < 64) {
            bool has = (keptw >> tid) & 1ull;
            u64 bal = __ballot(has);
            if (has) s_kb[__popcll(bal & ((1ull << tid) - 1ull))] = w * 64 + tid;
            if (tid == 0) s_kn = __popcll(keptw);
        }
        if (tid == 0) {
            int n = s_n;
            u64 bits = keptw;
            while (bits && n < POST) {
                int b = __builtin_ctzll(bits);
                bits &= bits - 1;
                list[n++] = w * 64 + b;
            }
            s_n = n;
        }
        __syncthreads();
        int kn = s_kn;
        int v = w + 1 + tid;
        if (v < 94 && kn) {
            u64 supp = 0;
            int t = 0;
            for (; t + 4 <= kn; t += 4) {
                u64 a0 = mimg[(size_t)s_kb[t] * MWORDS + v];
                u64 a1 = mimg[(size_t)s_kb[t + 1] * MWORDS + v];
                u64 a2 = mimg[(size_t)s_kb[t + 2] * MWORDS + v];
                u64 a3 = mimg[(size_t)s_kb[t + 3] * MWORDS + v];
                supp |= a0 | a1 | a2 | a3;
            }
            for (; t < kn; ++t) supp |= mimg[(size_t)s_kb[t] * MWORDS + v];
            keep[v] &= ~supp;
        }
        __syncthreads();
    }
    __syncthreads();
    int n = s_n;
    for (int e = tid; e < POST; e += 128) {
        float4 bx = (e < n) ? bbs[(size_t)img * PRE + list[e]] : make_float4(0, 0, 0, 0);
        *(float4*)&out2[((size_t)img * POST + e) * 4] = bx;
    }
}

extern "C" void kernel_launch(void* const* d_in, const int* in_sizes, int n_in,
                              void* d_out, int out_size, void* d_ws, size_t ws_size,
                              hipStream_t stream)
{
    const float* x     = (const float*)d_in[0];
    const float* w1    = (const float*)d_in[1];
    const float* b1    = (const float*)d_in[2];
    const float* sw    = (const float*)d_in[3];
    const float* sbias = (const float*)d_in[4];
    const float* lw    = (const float*)d_in[5];
    const float* lb    = (const float*)d_in[6];
    const int*   imh   = (const int*)d_in[7];
    const int*   imw   = (const int*)d_in[8];
    float* out = (float*)d_out;
    char* ws = (char*)d_ws;

    _Float16* wh2W = (_Float16*)(ws + 0);
    _Float16* wl2W = (_Float16*)(ws + 65536);
    _Float16* whW  = (_Float16*)(ws + 131072);
    _Float16* wlW  = (_Float16*)(ws + 4849664);
    _Float16* xhW  = (_Float16*)(ws + 9568256);
    _Float16* xlW  = (_Float16*)(ws + 25133056);
    float*    p0W     = (float*)(ws + 40697856);
    float*    p1W     = (float*)(ws + 71827456);
    float*    boxesW  = (float*)(ws + 102957056);
    float*    scoresW = (float*)(ws + 107334656);
    float*    sbW     = (float*)(ws + 108429056);
    float*    bbsW    = (float*)(ws + 108621056);
    float*    areasW  = (float*)(ws + 109389056);
    u32*      ghistW  = (u32*)(ws + 109581056);
    u32*      gccntW  = (u32*)(ws + 109589248);
    u32*      gprefW  = (u32*)(ws + 109589280);
    u32*      gremW   = (u32*)(ws + 109589312);
    u64*      arrW    = (u64*)(ws + 109597440);
    u64*      maskW   = (u64*)(ws + 40697856);   // overlays p0/p1 after hgemm

    float* out0 = out;            // rpn_locs   (8,34200,4)
    float* out1 = out + 1094400;  // rpn_scores (8,34200,2)
    float* out2 = out + 1641600;  // rois       (2400,4)
    float* out3 = out + 1651200;  // anchors    (34200,4)

    // select control state lives outside every overlay now -> safe to zero up front
    hipMemsetAsync(ws + 109581056, 0, 8224, stream);

    hipLaunchKernelGGL(k_split_w, dim3(512), dim3(256), 0, stream, w1, whW, wlW);
    hipLaunchKernelGGL(k_split_w2, dim3(64), dim3(512), 0, stream, lw, sw, wh2W, wl2W);
    for (int b = 0; b < 2; ++b) {
        hipLaunchKernelGGL(k_split_x, dim3(119, 16, 4), dim3(32, 8), 0, stream,
                           x + (size_t)b * 4 * CC * PP, xhW, xlW);
        hipLaunchKernelGGL(k_conv, dim3(960), dim3(256), 0, stream,
                           xhW, xlW, whW, wlW, p0W, p1W);
        hipLaunchKernelGGL(k_hgemm_post, dim3(60, 4), dim3(256), 0, stream,
                           p0W, p1W, b1, wh2W, wl2W, lb, sbias, imh, imw,
                           out0, out1, boxesW, scoresW, out3, 4 * b);
    }
    for (int pass = 0; pass < 4; ++pass) {
        int sh = 24 - 8 * pass;
        hipLaunchKernelGGL(k_sel_hist, dim3(8, NB), dim3(256), 0, stream,
                           scoresW, ghistW, gprefW, sh, pass);
        hipLaunchKernelGGL(k_sel_scan, dim3(NB), dim3(256), 0, stream,
                           ghistW, gprefW, gremW, sh, pass);
    }
    hipLaunchKernelGGL(k_sel_collect, dim3(8, NB), dim3(256), 0, stream,
                       scoresW, gprefW, gccntW, arrW);
    hipLaunchKernelGGL(k_sel_sort, dim3(NB), dim3(1024), NPAD * 8, stream,
                       scoresW, (const float4*)boxesW, arrW, gccntW,
                       sbW, (float4*)bbsW, areasW);
    hipLaunchKernelGGL(k_mask, dim3(94, 24, NB), dim3(256), 0, stream,
                       (const float4*)bbsW, areasW, maskW);
    hipLaunchKernelGGL(k_scan, dim3(NB), dim3(128), 0, stream,
                       sbW, (const float4*)bbsW, maskW, out2);
}

// Round 7
// 953.839 us; speedup vs baseline: 4.1200x; 4.1200x over previous
//
#include <hip/hip_runtime.h>
#include <stdint.h>
#include <math.h>

typedef unsigned long long u64;
typedef unsigned int u32;
typedef _Float16 half8 __attribute__((ext_vector_type(8)));
typedef float f32x4 __attribute__((ext_vector_type(4)));

#define CC   512
#define HH   50
#define WW2  76
#define PP   3800      // HH*WW2
#define NB   8
#define NA   34200     // PP*9
#define PRE  6000
#define POST 300
#define MWORDS 96      // u64 words per mask row (94 used, padded)
#define NPAD 8192      // bitonic sort size

// ---------------- workspace layout (bytes) ----------------
// wh2   @ 0            65,536      (64 x 512 f16)  [head weights hi]
// wl2   @ 65,536       65,536
// whF   @ 131,072      4,718,592   (frag-major conv weights hi: [g][kk][lane][8])
// wlF   @ 4,849,664    4,718,592
// xh    @ 9,568,256    15,564,800  (4 img * 3800 * 512 f16, per-batch)
// xl    @ 25,133,056   15,564,800
// --- after conv, xh/xl dead; overlay: ---
// boxes @ 17,350,656   4,377,600
// scores@ 21,728,256   1,094,400
// sb    @ 22,822,656     192,000
// bbs   @ 23,014,656     768,000
// areas @ 23,782,656     192,000
// fh    @ 40,697,856   31,129,600
// fl    @ 71,827,456   31,129,600
// --- after k_hgemm_post, fh/fl dead; overlay: ---
// mask  @ 40,697,856   36,864,000
// peak ~103 MB (<= 115.7 MB proven safe)

__device__ __forceinline__ u32 skey(float f) {
    u32 u = __float_as_uint(f);
    return (u & 0x80000000u) ? ~u : (u | 0x80000000u);
}

__device__ __forceinline__ float4 anchor_at(int p, int a) {
    const float rv[3] = {0.5f, 1.0f, 2.0f};
    const float sv[3] = {8.0f, 16.0f, 32.0f};
    int ri = a / 3, si = a % 3;
    float s16 = 16.0f * sv[si];
    float hh = s16 * sqrtf(rv[ri]);
    float ww = s16 * sqrtf(1.0f / rv[ri]);
    float bx1 = 8.0f - 0.5f * ww, by1 = 8.0f - 0.5f * hh;
    float bx2 = 8.0f + 0.5f * ww, by2 = 8.0f + 0.5f * hh;
    float sx = (float)((p % WW2) * 16);
    float sy = (float)((p / WW2) * 16);
    return make_float4(sx + bx1, sy + by1, sx + bx2, sy + by2);
}

// LDS slot swizzle for A staging: octet j of row m
__device__ __forceinline__ int lds_slot(int m, int j) {
    return (((m >> 4) * 64) + ((m & 15) ^ ((4 * (j & 1)) | (8 * (j >> 1)))) + (j << 4)) << 3;
}

// ---------------- kernel: split x into f16 hi/lo, transposed [p][c] --------------
// grid (119, 16, 4), block (32,8)
__global__ void k_split_x(const float* __restrict__ x, _Float16* __restrict__ xh,
                          _Float16* __restrict__ xl) {
    __shared__ float S[32][33];
    int zim = blockIdx.z;
    int p0 = blockIdx.x * 32, c0 = blockIdx.y * 32;
    int tx = threadIdx.x, ty0 = threadIdx.y;
    const float* xi = x + (size_t)zim * CC * PP;
#pragma unroll
    for (int yy = 0; yy < 32; yy += 8) {
        int cty = c0 + ty0 + yy, ptx = p0 + tx;
        S[ty0 + yy][tx] = (ptx < PP) ? xi[(size_t)cty * PP + ptx] : 0.f;
    }
    __syncthreads();
#pragma unroll
    for (int yy = 0; yy < 32; yy += 8) {
        int p = p0 + ty0 + yy;
        if (p < PP) {
            float v = S[tx][ty0 + yy];
            _Float16 h = (_Float16)v;
            float r = v - (float)h;
            size_t o = (size_t)(zim * PP + p) * 512 + c0 + tx;
            xh[o] = h;
            xl[o] = (_Float16)(r * 2048.0f);
        }
    }
}

// ---------------- kernel: split conv1 weights -> MFMA frag-major hi/lo -----------
__global__ void k_split_w(const float* __restrict__ w, _Float16* __restrict__ wh,
                          _Float16* __restrict__ wl) {
    __shared__ float S[4608];
    int co = blockIdx.x;
    for (int t = threadIdx.x; t < 4608; t += 256) S[t] = w[(size_t)co * 4608 + t];
    __syncthreads();
    int g = co >> 4, nlo = co & 15;
    for (int e = threadIdx.x; e < 4608; e += 256) {
        int cc = e / 9, idx = e - cc * 9;          // e enumerates (ci, idx)
        float v = S[cc * 9 + idx];
        _Float16 h = (_Float16)v;
        float r = v - (float)h;
        int kk = (cc >> 5) * 9 + idx;
        int lane = ((cc >> 3) & 3) * 16 + nlo;
        int j = cc & 7;
        size_t d = (((size_t)g * 144 + kk) * 64 + lane) * 8 + j;
        wh[d] = h;
        wl[d] = (_Float16)(r * 2048.0f);
    }
}

// ---------------- kernel: split head weights into [64][512] f16 hi/lo -----------
__global__ void k_split_w2(const float* __restrict__ lw, const float* __restrict__ sw,
                           _Float16* __restrict__ wh2, _Float16* __restrict__ wl2) {
    int row = blockIdx.x, k = threadIdx.x;
    float v = (row < 36) ? lw[row * 512 + k] : (row < 54 ? sw[(row - 36) * 512 + k] : 0.f);
    _Float16 h = (_Float16)v;
    float r = v - (float)h;
    wh2[row * 512 + k] = h;
    wl2[row * 512 + k] = (_Float16)(r * 2048.0f);
}

// ---------------- kernel: 3x3 conv via split-f16 MFMA implicit GEMM --------------
// 1-D grid 480 (XCD-pinned), block 256 (4 waves, 2x2), BM=BN=128, BK=32.
// PROVEN 231us form.  Register-file-bound at 2 blocks/CU (128 VGPR + 128 AGPR acc);
// do NOT raise launch_bounds min-waves (round-6: forced spill, 7.7x regression).
__global__ __launch_bounds__(256, 2) void k_conv(
    const _Float16* __restrict__ xh, const _Float16* __restrict__ xl,
    const _Float16* __restrict__ whF, const _Float16* __restrict__ wlF,
    const float* __restrict__ bias, _Float16* __restrict__ fh,
    _Float16* __restrict__ fl, int imgbase)
{
    __shared__ _Float16 lds[2 * 8192];
    const int tid = threadIdx.x;
    const int L = blockIdx.x;
    const int X = L & 7, q = L >> 3;          // q in 0..59
    const int nt = X & 3;
    const int zim = (X >> 2) * 2 + (q >= 30 ? 1 : 0);
    const int mt = q - (q >= 30 ? 30 : 0);
    const int m0 = mt * 128, n0 = nt * 128;
    const _Float16* xhi = xh + (size_t)zim * CC * PP;
    const _Float16* xlo = xl + (size_t)zim * CC * PP;

    const int mA0 = tid >> 2, jA0 = tid & 3;
    const int mA1 = 64 + (tid >> 2);

    f32x4 acc[4][4], acc2[4][4];
#pragma unroll
    for (int i = 0; i < 4; ++i)
#pragma unroll
        for (int j = 0; j < 4; ++j) {
            acc[i][j] = f32x4{0.f, 0.f, 0.f, 0.f};
            acc2[i][j] = f32x4{0.f, 0.f, 0.f, 0.f};
        }

    uint4 pa0h, pa0l, pa1h, pa1l;

    auto ld_a = [&](int m, int idx, int c0, uint4& vh, uint4& vl) {
        int dy = idx / 3 - 1, dx = idx % 3 - 1;
        int p = m0 + m;
        int px = p % 76, py = p / 76;
        bool av = (p < PP) && ((unsigned)(py + dy) < 50u) && ((unsigned)(px + dx) < 76u);
        if (av) {
            size_t off = (size_t)(p + dy * 76 + dx) * 512 + c0 + jA0 * 8;
            vh = *(const uint4*)(xhi + off);
            vl = *(const uint4*)(xlo + off);
        } else {
            vh = make_uint4(0, 0, 0, 0);
            vl = make_uint4(0, 0, 0, 0);
        }
    };
    auto stage_load = [&](int kk) {
        int c9 = kk / 9;                   // c-chunk outer, idx inner
        int idx = kk - c9 * 9;
        int c0 = c9 << 5;
        ld_a(mA0, idx, c0, pa0h, pa0l);
        ld_a(mA1, idx, c0, pa1h, pa1l);
    };
    const int sl0 = lds_slot(mA0, jA0);
    const int sl1 = lds_slot(mA1, jA0);
    auto stage_write = [&](int buf) {
        _Float16* Lp = lds + buf * 8192;
        *(uint4*)(Lp + sl0)        = pa0h;
        *(uint4*)(Lp + 4096 + sl0) = pa0l;
        *(uint4*)(Lp + sl1)        = pa1h;
        *(uint4*)(Lp + 4096 + sl1) = pa1l;
    };

    const int lane = tid & 63, wave = tid >> 6;
    const int wm = wave & 1, wn = wave >> 1;
    const int jr = lane >> 4;
    const int rd_off = (((lane & 15) ^ ((4 * (jr & 1)) | (8 * (jr >> 1)))) + (jr << 4)) << 3;
    const int g0 = nt * 8 + wn * 4;                 // base B frag index
    const size_t lane8 = (size_t)lane * 8;

    half8 b0h[4], b0l[4], b1h[4], b1l[4];
    auto load_b = [&](int kk, half8* bh_, half8* bl_) {
#pragma unroll
        for (int ni = 0; ni < 4; ++ni) {
            size_t off = (((size_t)(g0 + ni) * 144 + kk) * 64) * 8 + lane8;
            bh_[ni] = *(const half8*)(whF + off);
            bl_[ni] = *(const half8*)(wlF + off);
        }
    };

    auto compute = [&](int buf, const half8* bh, const half8* bl) {
        const _Float16* Lp = lds + buf * 8192;
        half8 ah[4], al[4];
#pragma unroll
        for (int mi = 0; mi < 4; ++mi) {
            int slot = (((wm * 4 + mi) * 64) << 3) + rd_off;
            ah[mi] = *(const half8*)(Lp + slot);
            al[mi] = *(const half8*)(Lp + 4096 + slot);
        }
#pragma unroll
        for (int ni = 0; ni < 4; ++ni) {
#pragma unroll
            for (int mi = 0; mi < 4; ++mi) {
                acc[mi][ni]  = __builtin_amdgcn_mfma_f32_16x16x32_f16(ah[mi], bh[ni], acc[mi][ni], 0, 0, 0);
                acc2[mi][ni] = __builtin_amdgcn_mfma_f32_16x16x32_f16(ah[mi], bl[ni], acc2[mi][ni], 0, 0, 0);
                acc2[mi][ni] = __builtin_amdgcn_mfma_f32_16x16x32_f16(al[mi], bh[ni], acc2[mi][ni], 0, 0, 0);
            }
        }
    };

    stage_load(0);
    stage_write(0);
    load_b(0, b0h, b0l);
    __syncthreads();
    // K loop unrolled by 2: explicit register ping-pong for B (no copies)
    for (int kk = 0; kk < 144; kk += 2) {
        // chunk kk (A buf = 0)
        stage_load(kk + 1);
        load_b(kk + 1, b1h, b1l);
        compute(0, b0h, b0l);
        stage_write(1);
        __syncthreads();
        // chunk kk+1 (A buf = 1)
        if (kk + 2 < 144) {
            stage_load(kk + 2);
            load_b(kk + 2, b0h, b0l);
        }
        compute(1, b1h, b1l);
        if (kk + 2 < 144) stage_write(0);
        __syncthreads();
    }

    const int qq = lane >> 4, cl = lane & 15;
    const size_t rowbase = (size_t)(imgbase + zim) * PP;
#pragma unroll
    for (int ni = 0; ni < 4; ++ni) {
        int n = n0 + (wn * 4 + ni) * 16 + cl;
        float bs = bias[n];
#pragma unroll
        for (int mi = 0; mi < 4; ++mi) {
            int mb = m0 + (wm * 4 + mi) * 16 + qq * 4;
            if (mb < PP) {
#pragma unroll
                for (int r = 0; r < 4; ++r) {
                    float v = fmaxf(acc[mi][ni][r] + acc2[mi][ni][r] * (1.f / 2048.f) + bs, 0.f);
                    _Float16 h = (_Float16)v;
                    float rr = v - (float)h;
                    size_t o = (rowbase + mb + r) * 512 + n;
                    fh[o] = h;
                    fl[o] = (_Float16)(rr * 2048.0f);
                }
            }
        }
    }
}

// ---------------- kernel: head GEMM + fused decode (k_post folded in) ------------
__global__ __launch_bounds__(256) void k_hgemm_post(
    const _Float16* __restrict__ fh, const _Float16* __restrict__ fl,
    const _Float16* __restrict__ wh2, const _Float16* __restrict__ wl2,
    const float* __restrict__ lb, const float* __restrict__ sbias,
    const int* __restrict__ imh_p, const int* __restrict__ imw_p,
    float* __restrict__ out0, float* __restrict__ out1,
    float* __restrict__ boxes, float* __restrict__ scores,
    float* __restrict__ out3)
{
    const int img = blockIdx.y;
    const int p0 = blockIdx.x * 64;
    const int wave = threadIdx.x >> 6, lane = threadIdx.x & 63;
    const int q8 = (lane >> 4) * 8;
    int arow = img * PP + p0 + wave * 16 + (lane & 15);
    if (arow >= NB * PP) arow = NB * PP - 1;
    const _Float16* fhp = fh + (size_t)arow * 512 + q8;
    const _Float16* flp = fl + (size_t)arow * 512 + q8;
    const _Float16* bhp = wh2 + (size_t)(lane & 15) * 512 + q8;
    const _Float16* blp = wl2 + (size_t)(lane & 15) * 512 + q8;

    f32x4 acc[4], acc2[4];
#pragma unroll
    for (int j = 0; j < 4; ++j) {
        acc[j] = f32x4{0.f, 0.f, 0.f, 0.f};
        acc2[j] = f32x4{0.f, 0.f, 0.f, 0.f};
    }

#pragma unroll 4
    for (int k0 = 0; k0 < 512; k0 += 32) {
        half8 ah = *(const half8*)(fhp + k0);
        half8 al = *(const half8*)(flp + k0);
#pragma unroll
        for (int nf = 0; nf < 4; ++nf) {
            half8 bh = *(const half8*)(bhp + (size_t)nf * 16 * 512 + k0);
            half8 bl = *(const half8*)(blp + (size_t)nf * 16 * 512 + k0);
            acc[nf]  = __builtin_amdgcn_mfma_f32_16x16x32_f16(ah, bh, acc[nf], 0, 0, 0);
            acc2[nf] = __builtin_amdgcn_mfma_f32_16x16x32_f16(ah, bl, acc2[nf], 0, 0, 0);
            acc2[nf] = __builtin_amdgcn_mfma_f32_16x16x32_f16(al, bh, acc2[nf], 0, 0, 0);
        }
    }

    // stage the 64x64 O tile to LDS
    __shared__ float Ls[64][68];
    const int q = lane >> 4, cl = lane & 15;
#pragma unroll
    for (int nf = 0; nf < 4; ++nf) {
        int n = nf * 16 + cl;
        float bs = (n < 36) ? lb[n] : (n < 54 ? sbias[n - 36] : 0.f);
#pragma unroll
        for (int r = 0; r < 4; ++r) {
            int ml = wave * 16 + q * 4 + r;
            Ls[ml][n] = acc[nf][r] + acc2[nf][r] * (1.f / 2048.f) + bs;
        }
    }
    __syncthreads();

    // decode: 64 rows x 9 anchors = 576 tasks over 256 threads
    const float fimh = (float)(*imh_p), fimw = (float)(*imw_p);
    for (int task = threadIdx.x; task < 576; task += 256) {
        int pl = task / 9, a = task - pl * 9;
        int p = p0 + pl;
        if (p >= PP) continue;
        float4 loc = *(const float4*)&Ls[pl][a * 4];
        float2 sc = make_float2(Ls[pl][36 + a * 2], Ls[pl][36 + a * 2 + 1]);
        size_t ai = (size_t)img * NA + (size_t)p * 9 + a;
        *(float4*)&out0[ai * 4] = loc;
        *(float2*)&out1[ai * 2] = sc;
        float mx = fmaxf(sc.x, sc.y);
        float e0 = expf(sc.x - mx), e1 = expf(sc.y - mx);
        float fg = e1 / (e0 + e1);
        float4 an = anchor_at(p, a);
        if (img == 0) ((float4*)out3)[p * 9 + a] = an;
        float aw = an.z - an.x, ah = an.w - an.y;
        float ax = an.x + 0.5f * aw, ay = an.y + 0.5f * ah;
        float cx = loc.x * aw + ax;
        float cy = loc.y * ah + ay;
        float wb = expf(loc.z) * aw, hb = expf(loc.w) * ah;
        float x1 = cx - 0.5f * wb, y1 = cy - 0.5f * hb;
        float x2 = cx + 0.5f * wb, y2 = cy + 0.5f * hb;
        x1 = fminf(fmaxf(x1, 0.f), fimw);
        x2 = fminf(fmaxf(x2, 0.f), fimw);
        y1 = fminf(fmaxf(y1, 0.f), fimh);
        y2 = fminf(fmaxf(y2, 0.f), fimh);
        bool valid = ((x2 - x1) >= 16.0f) && ((y2 - y1) >= 16.0f);
        ((float4*)boxes)[ai] = make_float4(x1, y1, x2, y2);
        scores[ai] = valid ? fg : -INFINITY;
    }
}

// ---------------- kernel: per-image top-6000 select + stable sort (LDS) ----------
// Monolith, one block/image.  Per-WAVE privatized histograms (16 x 256) cut the
// hot-bin LDS-atomic serialization ~16x (scores cluster near 0.5 -> 1-2 hot bins;
// this was the round-2 monolith's cost).  Collect uses the wave-aggregated
// compaction proven in rounds 3/5.  Bitonic sort restores the total order.
__global__ __launch_bounds__(1024) void k_select(
    const float* __restrict__ scores, const float4* __restrict__ boxes,
    float* __restrict__ sb, float4* __restrict__ bbs, float* __restrict__ areas)
{
    extern __shared__ u64 dyn[];
    u64* arr = dyn;                       // NPAD u64
    u32* hist = (u32*)(dyn + NPAD);       // 16 waves x 256 bins
    __shared__ u32 s_pref, s_rem, s_cnt;
    int img = blockIdx.x;
    int tid = threadIdx.x;
    const int lane = tid & 63, wv = tid >> 6;
    const float* sc = scores + (size_t)img * NA;
    const float4* sc4 = (const float4*)sc;
    if (tid == 0) { s_pref = 0; s_rem = PRE; }
    u32 pmask = 0;
    for (int sh = 24; sh >= 0; sh -= 8) {
        for (int i = tid; i < 16 * 256; i += 1024) hist[i] = 0;
        __syncthreads();
        u32 pref = s_pref;
        u32* wh = hist + wv * 256;
        for (int e4 = tid; e4 < NA / 4; e4 += 1024) {
            float4 s4 = sc4[e4];
            u32 k0 = skey(s4.x), k1 = skey(s4.y), k2 = skey(s4.z), k3 = skey(s4.w);
            if ((k0 & pmask) == pref) atomicAdd(&wh[(k0 >> sh) & 255], 1u);
            if ((k1 & pmask) == pref) atomicAdd(&wh[(k1 >> sh) & 255], 1u);
            if ((k2 & pmask) == pref) atomicAdd(&wh[(k2 >> sh) & 255], 1u);
            if ((k3 & pmask) == pref) atomicAdd(&wh[(k3 >> sh) & 255], 1u);
        }
        __syncthreads();
        if (tid < 256) {
            u32 s = 0;
#pragma unroll
            for (int w = 0; w < 16; ++w) s += hist[w * 256 + tid];
            hist[tid] = s;                // combined hist in wave-0 slot
        }
        __syncthreads();
        if (tid == 0) {
            u32 c = 0; u32 rem = s_rem; u32 pv = s_pref;
            for (int d = 255; d >= 0; --d) {
                u32 h = hist[d];
                if (c + h >= rem) { s_pref = pv | ((u32)d << sh); s_rem = rem - c; break; }
                c += h;
            }
        }
        __syncthreads();
        pmask |= (0xFFu << sh);
    }
    u32 T = s_pref;
    if (tid == 0) s_cnt = 0;
    __syncthreads();
    for (int e4 = tid; e4 < NA / 4; e4 += 1024) {
        float4 s4 = sc4[e4];
        u32 ks[4] = {skey(s4.x), skey(s4.y), skey(s4.z), skey(s4.w)};
#pragma unroll
        for (int v = 0; v < 4; ++v) {
            bool take = ks[v] >= T;
            u64 bal = __ballot(take);
            if (bal) {
                int leader = __builtin_ctzll(bal);
                u32 base = 0;
                if (lane == leader) base = atomicAdd(&s_cnt, (u32)__popcll(bal));
                base = (u32)__shfl((int)base, leader);
                if (take) {
                    u32 pos = base + (u32)__popcll(bal & ((1ull << lane) - 1ull));
                    if (pos < NPAD) arr[pos] = ((u64)ks[v] << 32) | (u64)(~(u32)(e4 * 4 + v));
                }
            }
        }
    }
    __syncthreads();
    u32 n = s_cnt; if (n > NPAD) n = NPAD;
    for (u32 t2 = n + tid; t2 < NPAD; t2 += 1024) arr[t2] = 0;
    for (u32 size = 2; size <= NPAD; size <<= 1) {
        for (u32 stride = size >> 1; stride > 0; stride >>= 1) {
            __syncthreads();
            for (u32 t2 = tid; t2 < NPAD / 2; t2 += 1024) {
                u32 i = 2 * t2 - (t2 & (stride - 1));
                u32 j = i + stride;
                u64 a = arr[i], b = arr[j];
                bool desc = ((i & size) == 0);
                if (desc ? (a < b) : (a > b)) { arr[i] = b; arr[j] = a; }
            }
        }
    }
    __syncthreads();
    for (int t2 = tid; t2 < PRE; t2 += 1024) {
        u64 v = arr[t2];
        u32 e = ~(u32)v;
        float s = sc[e];
        float4 bx = boxes[(size_t)img * NA + e];
        sb[img * PRE + t2] = s;
        bbs[img * PRE + t2] = bx;
        areas[img * PRE + t2] = (bx.z - bx.x) * (bx.w - bx.y);
    }
}

// ---------------- kernel: IoU suppression bitmask (upper-triangular tiles) -------
__global__ __launch_bounds__(256) void k_mask(
    const float4* __restrict__ bbs, const float* __restrict__ areas,
    u64* __restrict__ mask)
{
    int img = blockIdx.z, iT = blockIdx.x, jT = blockIdx.y;
    if (jT * 256 + 255 <= iT * 64) return;
    int tid = threadIdx.x;
    __shared__ float4 jb[256];
    __shared__ float ja[256];
    int jj = jT * 256 + tid;
    jb[tid] = (jj < PRE) ? bbs[(size_t)img * PRE + jj] : make_float4(0, 0, 0, 0);
    ja[tid] = (jj < PRE) ? areas[img * PRE + jj] : 0.f;
    __syncthreads();
    int i = iT * 64 + (tid & 63);
    int jw = jT * 4 + (tid >> 6);
    if (i >= PRE) return;
    float4 bi = bbs[(size_t)img * PRE + i];
    float ai = areas[img * PRE + i];
    int j0 = (tid >> 6) * 64;
    u64 m = 0;
#pragma unroll 4
    for (int b = 0; b < 64; ++b) {
        int j = jw * 64 + b;
        if (j >= PRE) break;
        if (j > i) {
            float4 bj = jb[j0 + b];
            float xx1 = fmaxf(bi.x, bj.x), yy1 = fmaxf(bi.y, bj.y);
            float xx2 = fminf(bi.z, bj.z), yy2 = fminf(bi.w, bj.w);
            float iw = fmaxf(xx2 - xx1, 0.f), ih2 = fmaxf(yy2 - yy1, 0.f);
            float inter = iw * ih2;
            float iou = inter / (ai + ja[j0 + b] - inter + 1e-9f);
            if (iou > 0.7f) m |= (1ull << b);
        }
    }
    mask[((size_t)img * PRE + i) * MWORDS + jw] = m;
}

// ---------------- kernel: chunked NMS scan — 64 boxes per serial step ------------
__global__ __launch_bounds__(128) void k_scan(
    const float* __restrict__ sb, const float4* __restrict__ bbs,
    const u64* __restrict__ mask, float* __restrict__ out2)
{
    const int img = blockIdx.x;
    const int tid = threadIdx.x;
    const int lane = tid & 63, wv = tid >> 6;
    __shared__ u64 keep[96];
    __shared__ u64 s_keptw;
    __shared__ int list[POST];
    __shared__ int s_n;
    __shared__ int s_kb[64];
    __shared__ int s_kn;

    for (int j0 = 0; j0 < PRE; j0 += 128) {
        int j = j0 + tid;
        bool alive = (j < PRE) && isfinite(sb[(size_t)img * PRE + j]);
        u64 bal = __ballot(alive);
        if (lane == 0) keep[(j0 >> 6) + wv] = bal;
    }
    if (tid == 0) { s_n = 0; keep[94] = 0; keep[95] = 0; }
    __syncthreads();

    const u64* mimg = mask + (size_t)img * PRE * MWORDS;
    for (int w = 0; w < 94; ++w) {
        if (s_n >= POST) break;
        if (wv == 0) {
            u64 myrow = mimg[(size_t)(w * 64 + lane) * MWORDS + w];
            u64 cur = keep[w];
            u64 keptw = 0;
            while (cur) {
                int b = __builtin_ctzll(cur);
                keptw |= 1ull << b;
                u64 row = __shfl(myrow, b);
                u64 hi = (b >= 63) ? 0ull : (~0ull << (b + 1));
                cur &= ~row & hi;
            }
            if (lane == 0) s_keptw = keptw;
        }
        __syncthreads();
        u64 keptw = s_keptw;
        // expand kept bit positions into an index list (wave 0)
        if (tid < 64) {
            bool has = (keptw >> tid) & 1ull;
            u64 bal = __ballot(has);
            if (has) s_kb[__popcll(bal & ((1ull << tid) - 1ull))] = w * 64 + tid;
            if (tid == 0) s_kn = __popcll(keptw);
        }
        if (tid == 0) {
            int n = s_n;
            u64 bits = keptw;
            while (bits && n < POST) {
                int b = __builtin_ctzll(bits);
                bits &= bits - 1;
                list[n++] = w * 64 + b;
            }
            s_n = n;
        }
        __syncthreads();
        int kn = s_kn;
        int v = w + 1 + tid;
        if (v < 94 && kn) {
            u64 supp = 0;
            int t = 0;
            for (; t + 4 <= kn; t += 4) {
                u64 a0 = mimg[(size_t)s_kb[t] * MWORDS + v];
                u64 a1 = mimg[(size_t)s_kb[t + 1] * MWORDS + v];
                u64 a2 = mimg[(size_t)s_kb[t + 2] * MWORDS + v];
                u64 a3 = mimg[(size_t)s_kb[t + 3] * MWORDS + v];
                supp |= a0 | a1 | a2 | a3;
            }
            for (; t < kn; ++t) supp |= mimg[(size_t)s_kb[t] * MWORDS + v];
            keep[v] &= ~supp;
        }
        __syncthreads();
    }
    __syncthreads();
    int n = s_n;
    for (int e = tid; e < POST; e += 128) {
        float4 bx = (e < n) ? bbs[(size_t)img * PRE + list[e]] : make_float4(0, 0, 0, 0);
        *(float4*)&out2[((size_t)img * POST + e) * 4] = bx;
    }
}

extern "C" void kernel_launch(void* const* d_in, const int* in_sizes, int n_in,
                              void* d_out, int out_size, void* d_ws, size_t ws_size,
                              hipStream_t stream)
{
    const float* x     = (const float*)d_in[0];
    const float* w1    = (const float*)d_in[1];
    const float* b1    = (const float*)d_in[2];
    const float* sw    = (const float*)d_in[3];
    const float* sbias = (const float*)d_in[4];
    const float* lw    = (const float*)d_in[5];
    const float* lb    = (const float*)d_in[6];
    const int*   imh   = (const int*)d_in[7];
    const int*   imw   = (const int*)d_in[8];
    float* out = (float*)d_out;
    char* ws = (char*)d_ws;

    _Float16* wh2W = (_Float16*)(ws + 0);
    _Float16* wl2W = (_Float16*)(ws + 65536);
    _Float16* whW  = (_Float16*)(ws + 131072);
    _Float16* wlW  = (_Float16*)(ws + 4849664);
    _Float16* xhW  = (_Float16*)(ws + 9568256);
    _Float16* xlW  = (_Float16*)(ws + 25133056);
    float*    boxesW  = (float*)(ws + 17350656);
    float*    scoresW = (float*)(ws + 21728256);
    float*    sbW     = (float*)(ws + 22822656);
    float*    bbsW    = (float*)(ws + 23014656);
    float*    areasW  = (float*)(ws + 23782656);
    _Float16* fhW  = (_Float16*)(ws + 40697856);
    _Float16* flW  = (_Float16*)(ws + 71827456);
    u64*      maskW   = (u64*)(ws + 40697856);

    float* out0 = out;            // rpn_locs   (8,34200,4)
    float* out1 = out + 1094400;  // rpn_scores (8,34200,2)
    float* out2 = out + 1641600;  // rois       (2400,4)
    float* out3 = out + 1651200;  // anchors    (34200,4)

    hipLaunchKernelGGL(k_split_w, dim3(512), dim3(256), 0, stream, w1, whW, wlW);
    hipLaunchKernelGGL(k_split_w2, dim3(64), dim3(512), 0, stream, lw, sw, wh2W, wl2W);
    for (int b = 0; b < 2; ++b) {
        hipLaunchKernelGGL(k_split_x, dim3(119, 16, 4), dim3(32, 8), 0, stream,
                           x + (size_t)b * 4 * CC * PP, xhW, xlW);
        hipLaunchKernelGGL(k_conv, dim3(480), dim3(256), 0, stream,
                           xhW, xlW, whW, wlW, b1, fhW, flW, b * 4);
    }
    hipLaunchKernelGGL(k_hgemm_post, dim3(60, NB), dim3(256), 0, stream,
                       fhW, flW, wh2W, wl2W, lb, sbias, imh, imw,
                       out0, out1, boxesW, scoresW, out3);
    hipLaunchKernelGGL(k_select, dim3(NB), dim3(1024), NPAD * 8 + 16 * 256 * 4, stream,
                       scoresW, (const float4*)boxesW, sbW, (float4*)bbsW, areasW);
    hipLaunchKernelGGL(k_mask, dim3(94, 24, NB), dim3(256), 0, stream,
                       (const float4*)bbsW, areasW, maskW);
    hipLaunchKernelGGL(k_scan, dim3(NB), dim3(128), 0, stream,
                       sbW, (const float4*)bbsW, maskW, out2);
}

// Round 8
// 906.748 us; speedup vs baseline: 4.3340x; 1.0519x over previous
//
#include <hip/hip_runtime.h>
#include <stdint.h>
#include <math.h>

typedef unsigned long long u64;
typedef unsigned int u32;
typedef _Float16 half8 __attribute__((ext_vector_type(8)));
typedef float f32x4 __attribute__((ext_vector_type(4)));

#define CC   512
#define HH   50
#define WW2  76
#define PP   3800      // HH*WW2
#define NB   8
#define NA   34200     // PP*9
#define PRE  6000
#define POST 300
#define MWORDS 96      // u64 words per mask row (94 used, padded)
#define NPAD 8192      // bitonic sort size
#define SCHUNK 1069    // float4-chunks per select block (8 blocks x 1069 >= 8550)

// ---------------- workspace layout (bytes) ----------------
// wh2   @ 0            65,536      (64 x 512 f16)  [head weights hi]
// wl2   @ 65,536       65,536
// whF   @ 131,072      4,718,592   (frag-major conv weights hi: [g][kk][lane][8])
// wlF   @ 4,849,664    4,718,592
// xh    @ 9,568,256    15,564,800  (4 img * 3800 * 512 f16, per-batch)
// xl    @ 25,133,056   15,564,800
// --- after conv, xh/xl dead; overlay: ---
// boxes @ 17,350,656   4,377,600
// scores@ 21,728,256   1,094,400
// sb    @ 22,822,656     192,000
// bbs   @ 23,014,656     768,000
// areas @ 23,782,656     192,000
// fh    @ 40,697,856   31,129,600
// fl    @ 71,827,456   31,129,600
// --- after k_hgemm_post, fh/fl dead; overlay: ---
// mask  @ 40,697,856   36,864,000  -> end 77,561,856
// selst @ 109,581,056     16,384   (ghist 8192 | gccnt | gpref | grem) - outside ALL overlays
// arr   @ 109,597,440    524,288   (NB x 8192 u64)
// peak ~110.1 MB (<= 115.7 MB proven safe)

__device__ __forceinline__ u32 skey(float f) {
    u32 u = __float_as_uint(f);
    return (u & 0x80000000u) ? ~u : (u | 0x80000000u);
}

__device__ __forceinline__ float4 anchor_at(int p, int a) {
    const float rv[3] = {0.5f, 1.0f, 2.0f};
    const float sv[3] = {8.0f, 16.0f, 32.0f};
    int ri = a / 3, si = a % 3;
    float s16 = 16.0f * sv[si];
    float hh = s16 * sqrtf(rv[ri]);
    float ww = s16 * sqrtf(1.0f / rv[ri]);
    float bx1 = 8.0f - 0.5f * ww, by1 = 8.0f - 0.5f * hh;
    float bx2 = 8.0f + 0.5f * ww, by2 = 8.0f + 0.5f * hh;
    float sx = (float)((p % WW2) * 16);
    float sy = (float)((p / WW2) * 16);
    return make_float4(sx + bx1, sy + by1, sx + bx2, sy + by2);
}

// LDS slot swizzle for A staging: octet j of row m
__device__ __forceinline__ int lds_slot(int m, int j) {
    return (((m >> 4) * 64) + ((m & 15) ^ ((4 * (j & 1)) | (8 * (j >> 1)))) + (j << 4)) << 3;
}

// ---------------- kernel: split x into f16 hi/lo, transposed [p][c] --------------
// grid (119, 16, 4), block (32,8)
__global__ void k_split_x(const float* __restrict__ x, _Float16* __restrict__ xh,
                          _Float16* __restrict__ xl) {
    __shared__ float S[32][33];
    int zim = blockIdx.z;
    int p0 = blockIdx.x * 32, c0 = blockIdx.y * 32;
    int tx = threadIdx.x, ty0 = threadIdx.y;
    const float* xi = x + (size_t)zim * CC * PP;
#pragma unroll
    for (int yy = 0; yy < 32; yy += 8) {
        int cty = c0 + ty0 + yy, ptx = p0 + tx;
        S[ty0 + yy][tx] = (ptx < PP) ? xi[(size_t)cty * PP + ptx] : 0.f;
    }
    __syncthreads();
#pragma unroll
    for (int yy = 0; yy < 32; yy += 8) {
        int p = p0 + ty0 + yy;
        if (p < PP) {
            float v = S[tx][ty0 + yy];
            _Float16 h = (_Float16)v;
            float r = v - (float)h;
            size_t o = (size_t)(zim * PP + p) * 512 + c0 + tx;
            xh[o] = h;
            xl[o] = (_Float16)(r * 2048.0f);
        }
    }
}

// ---------------- kernel: split conv1 weights -> MFMA frag-major hi/lo -----------
__global__ void k_split_w(const float* __restrict__ w, _Float16* __restrict__ wh,
                          _Float16* __restrict__ wl) {
    __shared__ float S[4608];
    int co = blockIdx.x;
    for (int t = threadIdx.x; t < 4608; t += 256) S[t] = w[(size_t)co * 4608 + t];
    __syncthreads();
    int g = co >> 4, nlo = co & 15;
    for (int e = threadIdx.x; e < 4608; e += 256) {
        int cc = e / 9, idx = e - cc * 9;          // e enumerates (ci, idx)
        float v = S[cc * 9 + idx];
        _Float16 h = (_Float16)v;
        float r = v - (float)h;
        int kk = (cc >> 5) * 9 + idx;
        int lane = ((cc >> 3) & 3) * 16 + nlo;
        int j = cc & 7;
        size_t d = (((size_t)g * 144 + kk) * 64 + lane) * 8 + j;
        wh[d] = h;
        wl[d] = (_Float16)(r * 2048.0f);
    }
}

// ---------------- kernel: split head weights into [64][512] f16 hi/lo -----------
__global__ void k_split_w2(const float* __restrict__ lw, const float* __restrict__ sw,
                           _Float16* __restrict__ wh2, _Float16* __restrict__ wl2) {
    int row = blockIdx.x, k = threadIdx.x;
    float v = (row < 36) ? lw[row * 512 + k] : (row < 54 ? sw[(row - 36) * 512 + k] : 0.f);
    _Float16 h = (_Float16)v;
    float r = v - (float)h;
    wh2[row * 512 + k] = h;
    wl2[row * 512 + k] = (_Float16)(r * 2048.0f);
}

// ---------------- kernel: 3x3 conv via split-f16 MFMA implicit GEMM --------------
// 1-D grid 480 (XCD-pinned), block 256 (4 waves, 2x2), BM=BN=128, BK=32.
// PROVEN 231us form.  Register-file-bound at 2 blocks/CU (128 VGPR + 128 AGPR acc);
// do NOT raise launch_bounds min-waves (round-6: forced spill, 7.7x regression).
__global__ __launch_bounds__(256, 2) void k_conv(
    const _Float16* __restrict__ xh, const _Float16* __restrict__ xl,
    const _Float16* __restrict__ whF, const _Float16* __restrict__ wlF,
    const float* __restrict__ bias, _Float16* __restrict__ fh,
    _Float16* __restrict__ fl, int imgbase)
{
    __shared__ _Float16 lds[2 * 8192];
    const int tid = threadIdx.x;
    const int L = blockIdx.x;
    const int X = L & 7, q = L >> 3;          // q in 0..59
    const int nt = X & 3;
    const int zim = (X >> 2) * 2 + (q >= 30 ? 1 : 0);
    const int mt = q - (q >= 30 ? 30 : 0);
    const int m0 = mt * 128, n0 = nt * 128;
    const _Float16* xhi = xh + (size_t)zim * CC * PP;
    const _Float16* xlo = xl + (size_t)zim * CC * PP;

    const int mA0 = tid >> 2, jA0 = tid & 3;
    const int mA1 = 64 + (tid >> 2);

    f32x4 acc[4][4], acc2[4][4];
#pragma unroll
    for (int i = 0; i < 4; ++i)
#pragma unroll
        for (int j = 0; j < 4; ++j) {
            acc[i][j] = f32x4{0.f, 0.f, 0.f, 0.f};
            acc2[i][j] = f32x4{0.f, 0.f, 0.f, 0.f};
        }

    uint4 pa0h, pa0l, pa1h, pa1l;

    auto ld_a = [&](int m, int idx, int c0, uint4& vh, uint4& vl) {
        int dy = idx / 3 - 1, dx = idx % 3 - 1;
        int p = m0 + m;
        int px = p % 76, py = p / 76;
        bool av = (p < PP) && ((unsigned)(py + dy) < 50u) && ((unsigned)(px + dx) < 76u);
        if (av) {
            size_t off = (size_t)(p + dy * 76 + dx) * 512 + c0 + jA0 * 8;
            vh = *(const uint4*)(xhi + off);
            vl = *(const uint4*)(xlo + off);
        } else {
            vh = make_uint4(0, 0, 0, 0);
            vl = make_uint4(0, 0, 0, 0);
        }
    };
    auto stage_load = [&](int kk) {
        int c9 = kk / 9;                   // c-chunk outer, idx inner
        int idx = kk - c9 * 9;
        int c0 = c9 << 5;
        ld_a(mA0, idx, c0, pa0h, pa0l);
        ld_a(mA1, idx, c0, pa1h, pa1l);
    };
    const int sl0 = lds_slot(mA0, jA0);
    const int sl1 = lds_slot(mA1, jA0);
    auto stage_write = [&](int buf) {
        _Float16* Lp = lds + buf * 8192;
        *(uint4*)(Lp + sl0)        = pa0h;
        *(uint4*)(Lp + 4096 + sl0) = pa0l;
        *(uint4*)(Lp + sl1)        = pa1h;
        *(uint4*)(Lp + 4096 + sl1) = pa1l;
    };

    const int lane = tid & 63, wave = tid >> 6;
    const int wm = wave & 1, wn = wave >> 1;
    const int jr = lane >> 4;
    const int rd_off = (((lane & 15) ^ ((4 * (jr & 1)) | (8 * (jr >> 1)))) + (jr << 4)) << 3;
    const int g0 = nt * 8 + wn * 4;                 // base B frag index
    const size_t lane8 = (size_t)lane * 8;

    half8 b0h[4], b0l[4], b1h[4], b1l[4];
    auto load_b = [&](int kk, half8* bh_, half8* bl_) {
#pragma unroll
        for (int ni = 0; ni < 4; ++ni) {
            size_t off = (((size_t)(g0 + ni) * 144 + kk) * 64) * 8 + lane8;
            bh_[ni] = *(const half8*)(whF + off);
            bl_[ni] = *(const half8*)(wlF + off);
        }
    };

    auto compute = [&](int buf, const half8* bh, const half8* bl) {
        const _Float16* Lp = lds + buf * 8192;
        half8 ah[4], al[4];
#pragma unroll
        for (int mi = 0; mi < 4; ++mi) {
            int slot = (((wm * 4 + mi) * 64) << 3) + rd_off;
            ah[mi] = *(const half8*)(Lp + slot);
            al[mi] = *(const half8*)(Lp + 4096 + slot);
        }
#pragma unroll
        for (int ni = 0; ni < 4; ++ni) {
#pragma unroll
            for (int mi = 0; mi < 4; ++mi) {
                acc[mi][ni]  = __builtin_amdgcn_mfma_f32_16x16x32_f16(ah[mi], bh[ni], acc[mi][ni], 0, 0, 0);
                acc2[mi][ni] = __builtin_amdgcn_mfma_f32_16x16x32_f16(ah[mi], bl[ni], acc2[mi][ni], 0, 0, 0);
                acc2[mi][ni] = __builtin_amdgcn_mfma_f32_16x16x32_f16(al[mi], bh[ni], acc2[mi][ni], 0, 0, 0);
            }
        }
    };

    stage_load(0);
    stage_write(0);
    load_b(0, b0h, b0l);
    __syncthreads();
    // K loop unrolled by 2: explicit register ping-pong for B (no copies)
    for (int kk = 0; kk < 144; kk += 2) {
        // chunk kk (A buf = 0)
        stage_load(kk + 1);
        load_b(kk + 1, b1h, b1l);
        compute(0, b0h, b0l);
        stage_write(1);
        __syncthreads();
        // chunk kk+1 (A buf = 1)
        if (kk + 2 < 144) {
            stage_load(kk + 2);
            load_b(kk + 2, b0h, b0l);
        }
        compute(1, b1h, b1l);
        if (kk + 2 < 144) stage_write(0);
        __syncthreads();
    }

    const int qq = lane >> 4, cl = lane & 15;
    const size_t rowbase = (size_t)(imgbase + zim) * PP;
#pragma unroll
    for (int ni = 0; ni < 4; ++ni) {
        int n = n0 + (wn * 4 + ni) * 16 + cl;
        float bs = bias[n];
#pragma unroll
        for (int mi = 0; mi < 4; ++mi) {
            int mb = m0 + (wm * 4 + mi) * 16 + qq * 4;
            if (mb < PP) {
#pragma unroll
                for (int r = 0; r < 4; ++r) {
                    float v = fmaxf(acc[mi][ni][r] + acc2[mi][ni][r] * (1.f / 2048.f) + bs, 0.f);
                    _Float16 h = (_Float16)v;
                    float rr = v - (float)h;
                    size_t o = (rowbase + mb + r) * 512 + n;
                    fh[o] = h;
                    fl[o] = (_Float16)(rr * 2048.0f);
                }
            }
        }
    }
}

// ---------------- kernel: head GEMM + fused decode (k_post folded in) ------------
__global__ __launch_bounds__(256) void k_hgemm_post(
    const _Float16* __restrict__ fh, const _Float16* __restrict__ fl,
    const _Float16* __restrict__ wh2, const _Float16* __restrict__ wl2,
    const float* __restrict__ lb, const float* __restrict__ sbias,
    const int* __restrict__ imh_p, const int* __restrict__ imw_p,
    float* __restrict__ out0, float* __restrict__ out1,
    float* __restrict__ boxes, float* __restrict__ scores,
    float* __restrict__ out3)
{
    const int img = blockIdx.y;
    const int p0 = blockIdx.x * 64;
    const int wave = threadIdx.x >> 6, lane = threadIdx.x & 63;
    const int q8 = (lane >> 4) * 8;
    int arow = img * PP + p0 + wave * 16 + (lane & 15);
    if (arow >= NB * PP) arow = NB * PP - 1;
    const _Float16* fhp = fh + (size_t)arow * 512 + q8;
    const _Float16* flp = fl + (size_t)arow * 512 + q8;
    const _Float16* bhp = wh2 + (size_t)(lane & 15) * 512 + q8;
    const _Float16* blp = wl2 + (size_t)(lane & 15) * 512 + q8;

    f32x4 acc[4], acc2[4];
#pragma unroll
    for (int j = 0; j < 4; ++j) {
        acc[j] = f32x4{0.f, 0.f, 0.f, 0.f};
        acc2[j] = f32x4{0.f, 0.f, 0.f, 0.f};
    }

#pragma unroll 4
    for (int k0 = 0; k0 < 512; k0 += 32) {
        half8 ah = *(const half8*)(fhp + k0);
        half8 al = *(const half8*)(flp + k0);
#pragma unroll
        for (int nf = 0; nf < 4; ++nf) {
            half8 bh = *(const half8*)(bhp + (size_t)nf * 16 * 512 + k0);
            half8 bl = *(const half8*)(blp + (size_t)nf * 16 * 512 + k0);
            acc[nf]  = __builtin_amdgcn_mfma_f32_16x16x32_f16(ah, bh, acc[nf], 0, 0, 0);
            acc2[nf] = __builtin_amdgcn_mfma_f32_16x16x32_f16(ah, bl, acc2[nf], 0, 0, 0);
            acc2[nf] = __builtin_amdgcn_mfma_f32_16x16x32_f16(al, bh, acc2[nf], 0, 0, 0);
        }
    }

    // stage the 64x64 O tile to LDS
    __shared__ float Ls[64][68];
    const int q = lane >> 4, cl = lane & 15;
#pragma unroll
    for (int nf = 0; nf < 4; ++nf) {
        int n = nf * 16 + cl;
        float bs = (n < 36) ? lb[n] : (n < 54 ? sbias[n - 36] : 0.f);
#pragma unroll
        for (int r = 0; r < 4; ++r) {
            int ml = wave * 16 + q * 4 + r;
            Ls[ml][n] = acc[nf][r] + acc2[nf][r] * (1.f / 2048.f) + bs;
        }
    }
    __syncthreads();

    // decode: 64 rows x 9 anchors = 576 tasks over 256 threads
    const float fimh = (float)(*imh_p), fimw = (float)(*imw_p);
    for (int task = threadIdx.x; task < 576; task += 256) {
        int pl = task / 9, a = task - pl * 9;
        int p = p0 + pl;
        if (p >= PP) continue;
        float4 loc = *(const float4*)&Ls[pl][a * 4];
        float2 sc = make_float2(Ls[pl][36 + a * 2], Ls[pl][36 + a * 2 + 1]);
        size_t ai = (size_t)img * NA + (size_t)p * 9 + a;
        *(float4*)&out0[ai * 4] = loc;
        *(float2*)&out1[ai * 2] = sc;
        float mx = fmaxf(sc.x, sc.y);
        float e0 = expf(sc.x - mx), e1 = expf(sc.y - mx);
        float fg = e1 / (e0 + e1);
        float4 an = anchor_at(p, a);
        if (img == 0) ((float4*)out3)[p * 9 + a] = an;
        float aw = an.z - an.x, ah = an.w - an.y;
        float ax = an.x + 0.5f * aw, ay = an.y + 0.5f * ah;
        float cx = loc.x * aw + ax;
        float cy = loc.y * ah + ay;
        float wb = expf(loc.z) * aw, hb = expf(loc.w) * ah;
        float x1 = cx - 0.5f * wb, y1 = cy - 0.5f * hb;
        float x2 = cx + 0.5f * wb, y2 = cy + 0.5f * hb;
        x1 = fminf(fmaxf(x1, 0.f), fimw);
        x2 = fminf(fmaxf(x2, 0.f), fimw);
        y1 = fminf(fmaxf(y1, 0.f), fimh);
        y2 = fminf(fmaxf(y2, 0.f), fimh);
        bool valid = ((x2 - x1) >= 16.0f) && ((y2 - y1) >= 16.0f);
        ((float4*)boxes)[ai] = make_float4(x1, y1, x2, y2);
        scores[ai] = valid ? fg : -INFINITY;
    }
}

// ================= selection pipeline (round-5 proven, ~122us total) =============

// ---- histogram pass: per-wave privatized LDS hist -> global atomics -------------
__global__ __launch_bounds__(256) void k_sel_hist(
    const float* __restrict__ scores, u32* __restrict__ ghist,
    const u32* __restrict__ gpref, int sh, int pass)
{
    __shared__ u32 wh[4][256];
    const int img = blockIdx.y, blk = blockIdx.x;
    const int tid = threadIdx.x, wv = tid >> 6;
#pragma unroll
    for (int w = 0; w < 4; ++w) wh[w][tid] = 0;
    __syncthreads();
    const u32 pmask = (pass == 0) ? 0u : (0xFFFFFFFFu << (sh + 8));
    const u32 pref = (pass == 0) ? 0u : gpref[img];
    const float4* sc4 = (const float4*)(scores + (size_t)img * NA);
    const int e40 = blk * SCHUNK;
    const int e41 = min(e40 + SCHUNK, NA / 4);
    for (int e4 = e40 + tid; e4 < e41; e4 += 256) {
        float4 s4 = sc4[e4];
        u32 kv[4] = {skey(s4.x), skey(s4.y), skey(s4.z), skey(s4.w)};
#pragma unroll
        for (int v = 0; v < 4; ++v)
            if ((kv[v] & pmask) == pref) atomicAdd(&wh[wv][(kv[v] >> sh) & 255u], 1u);
    }
    __syncthreads();
    u32 s = wh[0][tid] + wh[1][tid] + wh[2][tid] + wh[3][tid];
    if (s) atomicAdd(&ghist[img * 256 + tid], s);
}

// ---- scan pass: suffix-sum over 256 bins, pick digit, update pref/rem, re-zero --
__global__ __launch_bounds__(256) void k_sel_scan(
    u32* __restrict__ ghist, u32* __restrict__ gpref, u32* __restrict__ grem,
    int sh, int pass)
{
    __shared__ u32 A[256];
    __shared__ int s_d;
    const int img = blockIdx.x, t = threadIdx.x;
    u32 h = ghist[img * 256 + t];
    A[t] = h;
    if (t == 0) s_d = 0;
    __syncthreads();
    for (int off = 1; off < 256; off <<= 1) {
        u32 v = A[t] + ((t + off < 256) ? A[t + off] : 0u);
        __syncthreads();
        A[t] = v;
        __syncthreads();
    }
    const u32 rem = (pass == 0) ? (u32)PRE : grem[img];
    if (A[t] >= rem) atomicMax(&s_d, t);
    __syncthreads();
    if (t == 0) {
        int d = s_d;
        u32 snext = (d < 255) ? A[d + 1] : 0u;
        u32 pv = (pass == 0) ? 0u : gpref[img];
        gpref[img] = pv | ((u32)d << sh);
        grem[img] = rem - snext;
    }
    ghist[img * 256 + t] = 0;
}

// ---- collect: block-local LDS compaction, one global atomic per block -----------
__global__ __launch_bounds__(256) void k_sel_collect(
    const float* __restrict__ scores, const u32* __restrict__ gpref,
    u32* __restrict__ gccnt, u64* __restrict__ arr)
{
    __shared__ u64 lst[4288];
    __shared__ u32 s_c, s_base;
    const int img = blockIdx.y, blk = blockIdx.x;
    const int tid = threadIdx.x, lane = tid & 63;
    if (tid == 0) s_c = 0;
    __syncthreads();
    const u32 T = gpref[img];
    const float4* sc4 = (const float4*)(scores + (size_t)img * NA);
    const int e40 = blk * SCHUNK;
    const int e41 = min(e40 + SCHUNK, NA / 4);
    for (int e4 = e40 + tid; e4 < e41; e4 += 256) {
        float4 s4 = sc4[e4];
        u32 ks[4] = {skey(s4.x), skey(s4.y), skey(s4.z), skey(s4.w)};
#pragma unroll
        for (int v = 0; v < 4; ++v) {
            bool take = ks[v] >= T;
            u64 bal = __ballot(take);
            if (bal) {
                int leader = __builtin_ctzll(bal);
                u32 base = 0;
                if (lane == leader) base = atomicAdd(&s_c, (u32)__popcll(bal));
                base = (u32)__shfl((int)base, leader);
                if (take)
                    lst[base + (u32)__popcll(bal & ((1ull << lane) - 1ull))] =
                        ((u64)ks[v] << 32) | (u64)(~(u32)(e4 * 4 + v));
            }
        }
    }
    __syncthreads();
    if (tid == 0) s_base = atomicAdd(&gccnt[img], s_c);
    __syncthreads();
    const u32 base = s_base, c = s_c;
    u64* ar = arr + (size_t)img * NPAD;
    for (u32 t = tid; t < c; t += 256) {
        u32 pos = base + t;
        if (pos < NPAD) ar[pos] = lst[t];
    }
}

// ---- sort + output: bitonic over 8192 keys in LDS, gather boxes/areas -----------
__global__ __launch_bounds__(1024) void k_sel_sort(
    const float* __restrict__ scores, const float4* __restrict__ boxes,
    const u64* __restrict__ arr, const u32* __restrict__ gccnt,
    float* __restrict__ sb, float4* __restrict__ bbs, float* __restrict__ areas)
{
    extern __shared__ u64 dyn[];
    u64* a = dyn;
    const int img = blockIdx.x, tid = threadIdx.x;
    u32 n = gccnt[img]; if (n > NPAD) n = NPAD;
    const u64* ar = arr + (size_t)img * NPAD;
    for (int t = tid; t < NPAD; t += 1024) a[t] = ((u32)t < n) ? ar[t] : 0ull;
    for (u32 size = 2; size <= NPAD; size <<= 1) {
        for (u32 stride = size >> 1; stride > 0; stride >>= 1) {
            __syncthreads();
            for (u32 t2 = tid; t2 < NPAD / 2; t2 += 1024) {
                u32 i = 2 * t2 - (t2 & (stride - 1));
                u32 j = i + stride;
                u64 x = a[i], y = a[j];
                bool desc = ((i & size) == 0);
                if (desc ? (x < y) : (x > y)) { a[i] = y; a[j] = x; }
            }
        }
    }
    __syncthreads();
    const float* sc = scores + (size_t)img * NA;
    for (int t2 = tid; t2 < PRE; t2 += 1024) {
        u64 v = a[t2];
        u32 e = ~(u32)v;
        float s = sc[e];
        float4 bx = boxes[(size_t)img * NA + e];
        sb[img * PRE + t2] = s;
        bbs[img * PRE + t2] = bx;
        areas[img * PRE + t2] = (bx.z - bx.x) * (bx.w - bx.y);
    }
}

// ---------------- kernel: IoU suppression bitmask (upper-triangular tiles) -------
__global__ __launch_bounds__(256) void k_mask(
    const float4* __restrict__ bbs, const float* __restrict__ areas,
    u64* __restrict__ mask)
{
    int img = blockIdx.z, iT = blockIdx.x, jT = blockIdx.y;
    if (jT * 256 + 255 <= iT * 64) return;
    int tid = threadIdx.x;
    __shared__ float4 jb[256];
    __shared__ float ja[256];
    int jj = jT * 256 + tid;
    jb[tid] = (jj < PRE) ? bbs[(size_t)img * PRE + jj] : make_float4(0, 0, 0, 0);
    ja[tid] = (jj < PRE) ? areas[img * PRE + jj] : 0.f;
    __syncthreads();
    int i = iT * 64 + (tid & 63);
    int jw = jT * 4 + (tid >> 6);
    if (i >= PRE) return;
    float4 bi = bbs[(size_t)img * PRE + i];
    float ai = areas[img * PRE + i];
    int j0 = (tid >> 6) * 64;
    u64 m = 0;
#pragma unroll 4
    for (int b = 0; b < 64; ++b) {
        int j = jw * 64 + b;
        if (j >= PRE) break;
        if (j > i) {
            float4 bj = jb[j0 + b];
            float xx1 = fmaxf(bi.x, bj.x), yy1 = fmaxf(bi.y, bj.y);
            float xx2 = fminf(bi.z, bj.z), yy2 = fminf(bi.w, bj.w);
            float iw = fmaxf(xx2 - xx1, 0.f), ih2 = fmaxf(yy2 - yy1, 0.f);
            float inter = iw * ih2;
            float iou = inter / (ai + ja[j0 + b] - inter + 1e-9f);
            if (iou > 0.7f) m |= (1ull << b);
        }
    }
    mask[((size_t)img * PRE + i) * MWORDS + jw] = m;
}

// ---------------- kernel: NMS scan, on-demand suppression gather -----------------
// Per step w: supp_w = OR over the kept list (<=300) of mask[kept][w], gathered by
// 256 threads in parallel (1-2 load rounds) + wave shfl-OR reduce, replacing the
// old scatter-to-future phase whose per-thread serial kn-load loop dominated the
// critical path.  Diag bit-walk and append unchanged (greedy semantics identical).
__global__ __launch_bounds__(256) void k_scan(
    const float* __restrict__ sb, const float4* __restrict__ bbs,
    const u64* __restrict__ mask, float* __restrict__ out2)
{
    const int img = blockIdx.x;
    const int tid = threadIdx.x;
    const int lane = tid & 63, wv = tid >> 6;   // 4 waves
    __shared__ u64 alive[94];
    __shared__ int list[POST];
    __shared__ int s_n;
    __shared__ u64 wred[4];

    for (int j0 = 0; j0 < 94 * 64; j0 += 256) {
        int j = j0 + tid;
        bool al = (j < PRE) && isfinite(sb[(size_t)img * PRE + j]);
        u64 bal = __ballot(al);
        if (lane == 0) alive[(j0 >> 6) + wv] = bal;
    }
    if (tid == 0) s_n = 0;
    __syncthreads();

    const u64* mimg = mask + (size_t)img * PRE * MWORDS;
    for (int w = 0; w < 94; ++w) {
        int n = s_n;
        if (n >= POST) break;
        // prefetch diag row for this word (independent of supp)
        u64 myrow = 0;
        if (wv == 0) myrow = mimg[(size_t)(w * 64 + lane) * MWORDS + w];
        // gather suppression of word w from all previously-kept boxes
        u64 loc = 0;
        for (int t = tid; t < n; t += 256)
            loc |= mimg[(size_t)list[t] * MWORDS + w];
#pragma unroll
        for (int off = 32; off > 0; off >>= 1)
            loc |= __shfl_down(loc, off);
        if (lane == 0) wred[wv] = loc;
        __syncthreads();
        if (wv == 0) {
            u64 supp = wred[0] | wred[1] | wred[2] | wred[3];
            u64 cur = alive[w] & ~supp;
            u64 keptw = 0;
            while (cur) {
                int b = __builtin_ctzll(cur);
                keptw |= 1ull << b;
                u64 row = __shfl(myrow, b);
                u64 hi = (b >= 63) ? 0ull : (~0ull << (b + 1));
                cur &= ~row & hi;
            }
            if (lane == 0) {
                int nn = n;
                u64 bits = keptw;
                while (bits && nn < POST) {
                    int bb = __builtin_ctzll(bits);
                    bits &= bits - 1;
                    list[nn++] = w * 64 + bb;
                }
                s_n = nn;
            }
        }
        __syncthreads();
    }
    __syncthreads();
    int n = s_n;
    for (int e = tid; e < POST; e += 256) {
        float4 bx = (e < n) ? bbs[(size_t)img * PRE + list[e]] : make_float4(0, 0, 0, 0);
        *(float4*)&out2[((size_t)img * POST + e) * 4] = bx;
    }
}

extern "C" void kernel_launch(void* const* d_in, const int* in_sizes, int n_in,
                              void* d_out, int out_size, void* d_ws, size_t ws_size,
                              hipStream_t stream)
{
    const float* x     = (const float*)d_in[0];
    const float* w1    = (const float*)d_in[1];
    const float* b1    = (const float*)d_in[2];
    const float* sw    = (const float*)d_in[3];
    const float* sbias = (const float*)d_in[4];
    const float* lw    = (const float*)d_in[5];
    const float* lb    = (const float*)d_in[6];
    const int*   imh   = (const int*)d_in[7];
    const int*   imw   = (const int*)d_in[8];
    float* out = (float*)d_out;
    char* ws = (char*)d_ws;

    _Float16* wh2W = (_Float16*)(ws + 0);
    _Float16* wl2W = (_Float16*)(ws + 65536);
    _Float16* whW  = (_Float16*)(ws + 131072);
    _Float16* wlW  = (_Float16*)(ws + 4849664);
    _Float16* xhW  = (_Float16*)(ws + 9568256);
    _Float16* xlW  = (_Float16*)(ws + 25133056);
    float*    boxesW  = (float*)(ws + 17350656);
    float*    scoresW = (float*)(ws + 21728256);
    float*    sbW     = (float*)(ws + 22822656);
    float*    bbsW    = (float*)(ws + 23014656);
    float*    areasW  = (float*)(ws + 23782656);
    _Float16* fhW  = (_Float16*)(ws + 40697856);
    _Float16* flW  = (_Float16*)(ws + 71827456);
    u64*      maskW   = (u64*)(ws + 40697856);
    u32*      ghistW  = (u32*)(ws + 109581056);
    u32*      gccntW  = (u32*)(ws + 109589248);
    u32*      gprefW  = (u32*)(ws + 109589280);
    u32*      gremW   = (u32*)(ws + 109589312);
    u64*      arrW    = (u64*)(ws + 109597440);

    float* out0 = out;            // rpn_locs   (8,34200,4)
    float* out1 = out + 1094400;  // rpn_scores (8,34200,2)
    float* out2 = out + 1641600;  // rois       (2400,4)
    float* out3 = out + 1651200;  // anchors    (34200,4)

    // select control state lives outside every overlay -> safe to zero up front
    hipMemsetAsync(ws + 109581056, 0, 8224, stream);

    hipLaunchKernelGGL(k_split_w, dim3(512), dim3(256), 0, stream, w1, whW, wlW);
    hipLaunchKernelGGL(k_split_w2, dim3(64), dim3(512), 0, stream, lw, sw, wh2W, wl2W);
    for (int b = 0; b < 2; ++b) {
        hipLaunchKernelGGL(k_split_x, dim3(119, 16, 4), dim3(32, 8), 0, stream,
                           x + (size_t)b * 4 * CC * PP, xhW, xlW);
        hipLaunchKernelGGL(k_conv, dim3(480), dim3(256), 0, stream,
                           xhW, xlW, whW, wlW, b1, fhW, flW, b * 4);
    }
    hipLaunchKernelGGL(k_hgemm_post, dim3(60, NB), dim3(256), 0, stream,
                       fhW, flW, wh2W, wl2W, lb, sbias, imh, imw,
                       out0, out1, boxesW, scoresW, out3);
    for (int pass = 0; pass < 4; ++pass) {
        int sh = 24 - 8 * pass;
        hipLaunchKernelGGL(k_sel_hist, dim3(8, NB), dim3(256), 0, stream,
                           scoresW, ghistW, gprefW, sh, pass);
        hipLaunchKernelGGL(k_sel_scan, dim3(NB), dim3(256), 0, stream,
                           ghistW, gprefW, gremW, sh, pass);
    }
    hipLaunchKernelGGL(k_sel_collect, dim3(8, NB), dim3(256), 0, stream,
                       scoresW, gprefW, gccntW, arrW);
    hipLaunchKernelGGL(k_sel_sort, dim3(NB), dim3(1024), NPAD * 8, stream,
                       scoresW, (const float4*)boxesW, arrW, gccntW,
                       sbW, (float4*)bbsW, areasW);
    hipLaunchKernelGGL(k_mask, dim3(94, 24, NB), dim3(256), 0, stream,
                       (const float4*)bbsW, areasW, maskW);
    hipLaunchKernelGGL(k_scan, dim3(NB), dim3(256), 0, stream,
                       sbW, (const float4*)bbsW, maskW, out2);
}

// Round 10
// 863.781 us; speedup vs baseline: 4.5495x; 1.0497x over previous
//
#include <hip/hip_runtime.h>
#include <stdint.h>
#include <math.h>

typedef unsigned long long u64;
typedef unsigned int u32;
typedef _Float16 half8 __attribute__((ext_vector_type(8)));
typedef float f32x4 __attribute__((ext_vector_type(4)));

#define CC   512
#define HH   50
#define WW2  76
#define PP   3800      // HH*WW2
#define NB   8
#define NA   34200     // PP*9
#define PRE  6000
#define POST 300
#define MWORDS 96      // u64 words per mask row (94 used, padded)
#define NPAD 8192      // candidate buffer size per image
#define SHALF 4096     // per-block bitonic sort size (NPAD/2)
#define SCHUNK 1069    // float4-chunks per select block (8 blocks x 1069 >= 8550)

// ---------------- workspace layout (bytes) ----------------
// wh2   @ 0            65,536      (64 x 512 f16)  [head weights hi]
// wl2   @ 65,536       65,536
// whF   @ 131,072      4,718,592   (frag-major conv weights hi: [g][kk][lane][8])
// wlF   @ 4,849,664    4,718,592
// xh    @ 9,568,256    15,564,800  (4 img * 3800 * 512 f16, per-batch)
// xl    @ 25,133,056   15,564,800
// --- after conv, xh/xl dead; overlay: ---
// boxes @ 17,350,656   4,377,600
// scores@ 21,728,256   1,094,400
// sb    @ 22,822,656     192,000
// bbs   @ 23,014,656     768,000
// areas @ 23,782,656     192,000
// fh    @ 40,697,856   31,129,600
// fl    @ 71,827,456   31,129,600
// --- after k_hgemm_post, fh/fl dead; overlay: ---
// mask  @ 40,697,856   36,864,000  -> end 77,561,856
// selst @ 109,581,056     16,384   (ghist 8192 | gccnt | gpref | grem) - outside ALL overlays
// arr   @ 109,597,440    524,288   (NB x 8192 u64)
// peak ~110.1 MB (<= 115.7 MB proven safe)

__device__ __forceinline__ u32 skey(float f) {
    u32 u = __float_as_uint(f);
    return (u & 0x80000000u) ? ~u : (u | 0x80000000u);
}

__device__ __forceinline__ float4 anchor_at(int p, int a) {
    const float rv[3] = {0.5f, 1.0f, 2.0f};
    const float sv[3] = {8.0f, 16.0f, 32.0f};
    int ri = a / 3, si = a % 3;
    float s16 = 16.0f * sv[si];
    float hh = s16 * sqrtf(rv[ri]);
    float ww = s16 * sqrtf(1.0f / rv[ri]);
    float bx1 = 8.0f - 0.5f * ww, by1 = 8.0f - 0.5f * hh;
    float bx2 = 8.0f + 0.5f * ww, by2 = 8.0f + 0.5f * hh;
    float sx = (float)((p % WW2) * 16);
    float sy = (float)((p / WW2) * 16);
    return make_float4(sx + bx1, sy + by1, sx + bx2, sy + by2);
}

// LDS slot swizzle for A staging: octet j of row m
__device__ __forceinline__ int lds_slot(int m, int j) {
    return (((m >> 4) * 64) + ((m & 15) ^ ((4 * (j & 1)) | (8 * (j >> 1)))) + (j << 4)) << 3;
}

// ---------------- kernel: split x into f16 hi/lo, transposed [p][c] --------------
// grid (119, 16, 4), block (32,8)
__global__ void k_split_x(const float* __restrict__ x, _Float16* __restrict__ xh,
                          _Float16* __restrict__ xl) {
    __shared__ float S[32][33];
    int zim = blockIdx.z;
    int p0 = blockIdx.x * 32, c0 = blockIdx.y * 32;
    int tx = threadIdx.x, ty0 = threadIdx.y;
    const float* xi = x + (size_t)zim * CC * PP;
#pragma unroll
    for (int yy = 0; yy < 32; yy += 8) {
        int cty = c0 + ty0 + yy, ptx = p0 + tx;
        S[ty0 + yy][tx] = (ptx < PP) ? xi[(size_t)cty * PP + ptx] : 0.f;
    }
    __syncthreads();
#pragma unroll
    for (int yy = 0; yy < 32; yy += 8) {
        int p = p0 + ty0 + yy;
        if (p < PP) {
            float v = S[tx][ty0 + yy];
            _Float16 h = (_Float16)v;
            float r = v - (float)h;
            size_t o = (size_t)(zim * PP + p) * 512 + c0 + tx;
            xh[o] = h;
            xl[o] = (_Float16)(r * 2048.0f);
        }
    }
}

// ---------------- kernel: split conv1 weights -> MFMA frag-major hi/lo -----------
__global__ void k_split_w(const float* __restrict__ w, _Float16* __restrict__ wh,
                          _Float16* __restrict__ wl) {
    __shared__ float S[4608];
    int co = blockIdx.x;
    for (int t = threadIdx.x; t < 4608; t += 256) S[t] = w[(size_t)co * 4608 + t];
    __syncthreads();
    int g = co >> 4, nlo = co & 15;
    for (int e = threadIdx.x; e < 4608; e += 256) {
        int cc = e / 9, idx = e - cc * 9;          // e enumerates (ci, idx)
        float v = S[cc * 9 + idx];
        _Float16 h = (_Float16)v;
        float r = v - (float)h;
        int kk = (cc >> 5) * 9 + idx;
        int lane = ((cc >> 3) & 3) * 16 + nlo;
        int j = cc & 7;
        size_t d = (((size_t)g * 144 + kk) * 64 + lane) * 8 + j;
        wh[d] = h;
        wl[d] = (_Float16)(r * 2048.0f);
    }
}

// ---------------- kernel: split head weights into [64][512] f16 hi/lo -----------
__global__ void k_split_w2(const float* __restrict__ lw, const float* __restrict__ sw,
                           _Float16* __restrict__ wh2, _Float16* __restrict__ wl2) {
    int row = blockIdx.x, k = threadIdx.x;
    float v = (row < 36) ? lw[row * 512 + k] : (row < 54 ? sw[(row - 36) * 512 + k] : 0.f);
    _Float16 h = (_Float16)v;
    float r = v - (float)h;
    wh2[row * 512 + k] = h;
    wl2[row * 512 + k] = (_Float16)(r * 2048.0f);
}

// ---------------- kernel: 3x3 conv via split-f16 MFMA implicit GEMM --------------
// 1-D grid 480 (XCD-pinned), block 256 (4 waves, 2x2), BM=BN=128, BK=32.
// PROVEN 231us form.  Register-file-bound at 2 blocks/CU (128 VGPR + 128 AGPR acc).
// Final verdict: do NOT restructure (round-6 spill 7.7x; round-9 big-LDS pipeline
// killed the container).  This is the 2-phase structure's ceiling (~941 TF eff).
__global__ __launch_bounds__(256, 2) void k_conv(
    const _Float16* __restrict__ xh, const _Float16* __restrict__ xl,
    const _Float16* __restrict__ whF, const _Float16* __restrict__ wlF,
    const float* __restrict__ bias, _Float16* __restrict__ fh,
    _Float16* __restrict__ fl, int imgbase)
{
    __shared__ _Float16 lds[2 * 8192];
    const int tid = threadIdx.x;
    const int L = blockIdx.x;
    const int X = L & 7, q = L >> 3;          // q in 0..59
    const int nt = X & 3;
    const int zim = (X >> 2) * 2 + (q >= 30 ? 1 : 0);
    const int mt = q - (q >= 30 ? 30 : 0);
    const int m0 = mt * 128, n0 = nt * 128;
    const _Float16* xhi = xh + (size_t)zim * CC * PP;
    const _Float16* xlo = xl + (size_t)zim * CC * PP;

    const int mA0 = tid >> 2, jA0 = tid & 3;
    const int mA1 = 64 + (tid >> 2);

    f32x4 acc[4][4], acc2[4][4];
#pragma unroll
    for (int i = 0; i < 4; ++i)
#pragma unroll
        for (int j = 0; j < 4; ++j) {
            acc[i][j] = f32x4{0.f, 0.f, 0.f, 0.f};
            acc2[i][j] = f32x4{0.f, 0.f, 0.f, 0.f};
        }

    uint4 pa0h, pa0l, pa1h, pa1l;

    auto ld_a = [&](int m, int idx, int c0, uint4& vh, uint4& vl) {
        int dy = idx / 3 - 1, dx = idx % 3 - 1;
        int p = m0 + m;
        int px = p % 76, py = p / 76;
        bool av = (p < PP) && ((unsigned)(py + dy) < 50u) && ((unsigned)(px + dx) < 76u);
        if (av) {
            size_t off = (size_t)(p + dy * 76 + dx) * 512 + c0 + jA0 * 8;
            vh = *(const uint4*)(xhi + off);
            vl = *(const uint4*)(xlo + off);
        } else {
            vh = make_uint4(0, 0, 0, 0);
            vl = make_uint4(0, 0, 0, 0);
        }
    };
    auto stage_load = [&](int kk) {
        int c9 = kk / 9;                   // c-chunk outer, idx inner
        int idx = kk - c9 * 9;
        int c0 = c9 << 5;
        ld_a(mA0, idx, c0, pa0h, pa0l);
        ld_a(mA1, idx, c0, pa1h, pa1l);
    };
    const int sl0 = lds_slot(mA0, jA0);
    const int sl1 = lds_slot(mA1, jA0);
    auto stage_write = [&](int buf) {
        _Float16* Lp = lds + buf * 8192;
        *(uint4*)(Lp + sl0)        = pa0h;
        *(uint4*)(Lp + 4096 + sl0) = pa0l;
        *(uint4*)(Lp + sl1)        = pa1h;
        *(uint4*)(Lp + 4096 + sl1) = pa1l;
    };

    const int lane = tid & 63, wave = tid >> 6;
    const int wm = wave & 1, wn = wave >> 1;
    const int jr = lane >> 4;
    const int rd_off = (((lane & 15) ^ ((4 * (jr & 1)) | (8 * (jr >> 1)))) + (jr << 4)) << 3;
    const int g0 = nt * 8 + wn * 4;                 // base B frag index
    const size_t lane8 = (size_t)lane * 8;

    half8 b0h[4], b0l[4], b1h[4], b1l[4];
    auto load_b = [&](int kk, half8* bh_, half8* bl_) {
#pragma unroll
        for (int ni = 0; ni < 4; ++ni) {
            size_t off = (((size_t)(g0 + ni) * 144 + kk) * 64) * 8 + lane8;
            bh_[ni] = *(const half8*)(whF + off);
            bl_[ni] = *(const half8*)(wlF + off);
        }
    };

    auto compute = [&](int buf, const half8* bh, const half8* bl) {
        const _Float16* Lp = lds + buf * 8192;
        half8 ah[4], al[4];
#pragma unroll
        for (int mi = 0; mi < 4; ++mi) {
            int slot = (((wm * 4 + mi) * 64) << 3) + rd_off;
            ah[mi] = *(const half8*)(Lp + slot);
            al[mi] = *(const half8*)(Lp + 4096 + slot);
        }
#pragma unroll
        for (int ni = 0; ni < 4; ++ni) {
#pragma unroll
            for (int mi = 0; mi < 4; ++mi) {
                acc[mi][ni]  = __builtin_amdgcn_mfma_f32_16x16x32_f16(ah[mi], bh[ni], acc[mi][ni], 0, 0, 0);
                acc2[mi][ni] = __builtin_amdgcn_mfma_f32_16x16x32_f16(ah[mi], bl[ni], acc2[mi][ni], 0, 0, 0);
                acc2[mi][ni] = __builtin_amdgcn_mfma_f32_16x16x32_f16(al[mi], bh[ni], acc2[mi][ni], 0, 0, 0);
            }
        }
    };

    stage_load(0);
    stage_write(0);
    load_b(0, b0h, b0l);
    __syncthreads();
    // K loop unrolled by 2: explicit register ping-pong for B (no copies)
    for (int kk = 0; kk < 144; kk += 2) {
        // chunk kk (A buf = 0)
        stage_load(kk + 1);
        load_b(kk + 1, b1h, b1l);
        compute(0, b0h, b0l);
        stage_write(1);
        __syncthreads();
        // chunk kk+1 (A buf = 1)
        if (kk + 2 < 144) {
            stage_load(kk + 2);
            load_b(kk + 2, b0h, b0l);
        }
        compute(1, b1h, b1l);
        if (kk + 2 < 144) stage_write(0);
        __syncthreads();
    }

    const int qq = lane >> 4, cl = lane & 15;
    const size_t rowbase = (size_t)(imgbase + zim) * PP;
#pragma unroll
    for (int ni = 0; ni < 4; ++ni) {
        int n = n0 + (wn * 4 + ni) * 16 + cl;
        float bs = bias[n];
#pragma unroll
        for (int mi = 0; mi < 4; ++mi) {
            int mb = m0 + (wm * 4 + mi) * 16 + qq * 4;
            if (mb < PP) {
#pragma unroll
                for (int r = 0; r < 4; ++r) {
                    float v = fmaxf(acc[mi][ni][r] + acc2[mi][ni][r] * (1.f / 2048.f) + bs, 0.f);
                    _Float16 h = (_Float16)v;
                    float rr = v - (float)h;
                    size_t o = (rowbase + mb + r) * 512 + n;
                    fh[o] = h;
                    fl[o] = (_Float16)(rr * 2048.0f);
                }
            }
        }
    }
}

// ---------------- kernel: head GEMM + fused decode (k_post folded in) ------------
__global__ __launch_bounds__(256) void k_hgemm_post(
    const _Float16* __restrict__ fh, const _Float16* __restrict__ fl,
    const _Float16* __restrict__ wh2, const _Float16* __restrict__ wl2,
    const float* __restrict__ lb, const float* __restrict__ sbias,
    const int* __restrict__ imh_p, const int* __restrict__ imw_p,
    float* __restrict__ out0, float* __restrict__ out1,
    float* __restrict__ boxes, float* __restrict__ scores,
    float* __restrict__ out3)
{
    const int img = blockIdx.y;
    const int p0 = blockIdx.x * 64;
    const int wave = threadIdx.x >> 6, lane = threadIdx.x & 63;
    const int q8 = (lane >> 4) * 8;
    int arow = img * PP + p0 + wave * 16 + (lane & 15);
    if (arow >= NB * PP) arow = NB * PP - 1;
    const _Float16* fhp = fh + (size_t)arow * 512 + q8;
    const _Float16* flp = fl + (size_t)arow * 512 + q8;
    const _Float16* bhp = wh2 + (size_t)(lane & 15) * 512 + q8;
    const _Float16* blp = wl2 + (size_t)(lane & 15) * 512 + q8;

    f32x4 acc[4], acc2[4];
#pragma unroll
    for (int j = 0; j < 4; ++j) {
        acc[j] = f32x4{0.f, 0.f, 0.f, 0.f};
        acc2[j] = f32x4{0.f, 0.f, 0.f, 0.f};
    }

#pragma unroll 4
    for (int k0 = 0; k0 < 512; k0 += 32) {
        half8 ah = *(const half8*)(fhp + k0);
        half8 al = *(const half8*)(flp + k0);
#pragma unroll
        for (int nf = 0; nf < 4; ++nf) {
            half8 bh = *(const half8*)(bhp + (size_t)nf * 16 * 512 + k0);
            half8 bl = *(const half8*)(blp + (size_t)nf * 16 * 512 + k0);
            acc[nf]  = __builtin_amdgcn_mfma_f32_16x16x32_f16(ah, bh, acc[nf], 0, 0, 0);
            acc2[nf] = __builtin_amdgcn_mfma_f32_16x16x32_f16(ah, bl, acc2[nf], 0, 0, 0);
            acc2[nf] = __builtin_amdgcn_mfma_f32_16x16x32_f16(al, bh, acc2[nf], 0, 0, 0);
        }
    }

    // stage the 64x64 O tile to LDS
    __shared__ float Ls[64][68];
    const int q = lane >> 4, cl = lane & 15;
#pragma unroll
    for (int nf = 0; nf < 4; ++nf) {
        int n = nf * 16 + cl;
        float bs = (n < 36) ? lb[n] : (n < 54 ? sbias[n - 36] : 0.f);
#pragma unroll
        for (int r = 0; r < 4; ++r) {
            int ml = wave * 16 + q * 4 + r;
            Ls[ml][n] = acc[nf][r] + acc2[nf][r] * (1.f / 2048.f) + bs;
        }
    }
    __syncthreads();

    // decode: 64 rows x 9 anchors = 576 tasks over 256 threads
    const float fimh = (float)(*imh_p), fimw = (float)(*imw_p);
    for (int task = threadIdx.x; task < 576; task += 256) {
        int pl = task / 9, a = task - pl * 9;
        int p = p0 + pl;
        if (p >= PP) continue;
        float4 loc = *(const float4*)&Ls[pl][a * 4];
        float2 sc = make_float2(Ls[pl][36 + a * 2], Ls[pl][36 + a * 2 + 1]);
        size_t ai = (size_t)img * NA + (size_t)p * 9 + a;
        *(float4*)&out0[ai * 4] = loc;
        *(float2*)&out1[ai * 2] = sc;
        float mx = fmaxf(sc.x, sc.y);
        float e0 = expf(sc.x - mx), e1 = expf(sc.y - mx);
        float fg = e1 / (e0 + e1);
        float4 an = anchor_at(p, a);
        if (img == 0) ((float4*)out3)[p * 9 + a] = an;
        float aw = an.z - an.x, ah = an.w - an.y;
        float ax = an.x + 0.5f * aw, ay = an.y + 0.5f * ah;
        float cx = loc.x * aw + ax;
        float cy = loc.y * ah + ay;
        float wb = expf(loc.z) * aw, hb = expf(loc.w) * ah;
        float x1 = cx - 0.5f * wb, y1 = cy - 0.5f * hb;
        float x2 = cx + 0.5f * wb, y2 = cy + 0.5f * hb;
        x1 = fminf(fmaxf(x1, 0.f), fimw);
        x2 = fminf(fmaxf(x2, 0.f), fimw);
        y1 = fminf(fmaxf(y1, 0.f), fimh);
        y2 = fminf(fmaxf(y2, 0.f), fimh);
        bool valid = ((x2 - x1) >= 16.0f) && ((y2 - y1) >= 16.0f);
        ((float4*)boxes)[ai] = make_float4(x1, y1, x2, y2);
        scores[ai] = valid ? fg : -INFINITY;
    }
}

// ================= selection pipeline ============================================

// ---- histogram pass: per-wave privatized LDS hist -> global atomics -------------
__global__ __launch_bounds__(256) void k_sel_hist(
    const float* __restrict__ scores, u32* __restrict__ ghist,
    const u32* __restrict__ gpref, int sh, int pass)
{
    __shared__ u32 wh[4][256];
    const int img = blockIdx.y, blk = blockIdx.x;
    const int tid = threadIdx.x, wv = tid >> 6;
#pragma unroll
    for (int w = 0; w < 4; ++w) wh[w][tid] = 0;
    __syncthreads();
    const u32 pmask = (pass == 0) ? 0u : (0xFFFFFFFFu << (sh + 8));
    const u32 pref = (pass == 0) ? 0u : gpref[img];
    const float4* sc4 = (const float4*)(scores + (size_t)img * NA);
    const int e40 = blk * SCHUNK;
    const int e41 = min(e40 + SCHUNK, NA / 4);
    for (int e4 = e40 + tid; e4 < e41; e4 += 256) {
        float4 s4 = sc4[e4];
        u32 kv[4] = {skey(s4.x), skey(s4.y), skey(s4.z), skey(s4.w)};
#pragma unroll
        for (int v = 0; v < 4; ++v)
            if ((kv[v] & pmask) == pref) atomicAdd(&wh[wv][(kv[v] >> sh) & 255u], 1u);
    }
    __syncthreads();
    u32 s = wh[0][tid] + wh[1][tid] + wh[2][tid] + wh[3][tid];
    if (s) atomicAdd(&ghist[img * 256 + tid], s);
}

// ---- scan pass: suffix-sum over 256 bins, pick digit, update pref/rem, re-zero --
__global__ __launch_bounds__(256) void k_sel_scan(
    u32* __restrict__ ghist, u32* __restrict__ gpref, u32* __restrict__ grem,
    int sh, int pass)
{
    __shared__ u32 A[256];
    __shared__ int s_d;
    const int img = blockIdx.x, t = threadIdx.x;
    u32 h = ghist[img * 256 + t];
    A[t] = h;
    if (t == 0) s_d = 0;
    __syncthreads();
    for (int off = 1; off < 256; off <<= 1) {
        u32 v = A[t] + ((t + off < 256) ? A[t + off] : 0u);
        __syncthreads();
        A[t] = v;
        __syncthreads();
    }
    const u32 rem = (pass == 0) ? (u32)PRE : grem[img];
    if (A[t] >= rem) atomicMax(&s_d, t);
    __syncthreads();
    if (t == 0) {
        int d = s_d;
        u32 snext = (d < 255) ? A[d + 1] : 0u;
        u32 pv = (pass == 0) ? 0u : gpref[img];
        gpref[img] = pv | ((u32)d << sh);
        grem[img] = rem - snext;
    }
    ghist[img * 256 + t] = 0;
}

// ---- collect: block-local LDS compaction, one global atomic per block -----------
__global__ __launch_bounds__(256) void k_sel_collect(
    const float* __restrict__ scores, const u32* __restrict__ gpref,
    u32* __restrict__ gccnt, u64* __restrict__ arr)
{
    __shared__ u64 lst[4288];
    __shared__ u32 s_c, s_base;
    const int img = blockIdx.y, blk = blockIdx.x;
    const int tid = threadIdx.x, lane = tid & 63;
    if (tid == 0) s_c = 0;
    __syncthreads();
    const u32 T = gpref[img];
    const float4* sc4 = (const float4*)(scores + (size_t)img * NA);
    const int e40 = blk * SCHUNK;
    const int e41 = min(e40 + SCHUNK, NA / 4);
    for (int e4 = e40 + tid; e4 < e41; e4 += 256) {
        float4 s4 = sc4[e4];
        u32 ks[4] = {skey(s4.x), skey(s4.y), skey(s4.z), skey(s4.w)};
#pragma unroll
        for (int v = 0; v < 4; ++v) {
            bool take = ks[v] >= T;
            u64 bal = __ballot(take);
            if (bal) {
                int leader = __builtin_ctzll(bal);
                u32 base = 0;
                if (lane == leader) base = atomicAdd(&s_c, (u32)__popcll(bal));
                base = (u32)__shfl((int)base, leader);
                if (take)
                    lst[base + (u32)__popcll(bal & ((1ull << lane) - 1ull))] =
                        ((u64)ks[v] << 32) | (u64)(~(u32)(e4 * 4 + v));
            }
        }
    }
    __syncthreads();
    if (tid == 0) s_base = atomicAdd(&gccnt[img], s_c);
    __syncthreads();
    const u32 base = s_base, c = s_c;
    u64* ar = arr + (size_t)img * NPAD;
    for (u32 t = tid; t < c; t += 256) {
        u32 pos = base + t;
        if (pos < NPAD) ar[pos] = lst[t];
    }
}

// ---- sub-sort: each block bitonic-sorts one 4096-half descending, in place ------
// Keys ((skey<<32)|~idx) are globally unique (idx unique); invalid slots set to 0
// (every real key > 0: positive scores -> top bits >= 0x8000_0000, -inf -> 0x007FFFFF).
__global__ __launch_bounds__(1024) void k_sel_sort2(
    u64* __restrict__ arr, const u32* __restrict__ gccnt)
{
    __shared__ u64 a[SHALF];
    const int img = blockIdx.y, half = blockIdx.x;
    const int tid = threadIdx.x;
    u32 n = gccnt[img]; if (n > NPAD) n = NPAD;
    u64* ar = arr + (size_t)img * NPAD + (size_t)half * SHALF;
    const int base = half * SHALF;
    for (int t = tid; t < SHALF; t += 1024)
        a[t] = ((u32)(base + t) < n) ? ar[t] : 0ull;
    for (u32 size = 2; size <= SHALF; size <<= 1) {
        for (u32 stride = size >> 1; stride > 0; stride >>= 1) {
            __syncthreads();
            for (u32 t2 = tid; t2 < SHALF / 2; t2 += 1024) {
                u32 i = 2 * t2 - (t2 & (stride - 1));
                u32 j = i + stride;
                u64 x = a[i], y = a[j];
                bool desc = ((i & size) == 0);
                if (desc ? (x < y) : (x > y)) { a[i] = y; a[j] = x; }
            }
        }
    }
    __syncthreads();
    for (int t = tid; t < SHALF; t += 1024) ar[t] = a[t];
}

// ---- merge: rank-t output via merge-path co-rank over the two sorted halves -----
// All keys distinct (idx unique); 0-pads lose to every real key and >=PRE real
// keys exist (threshold invariant), so ranks [0,PRE) always hit real elements.
__global__ __launch_bounds__(1024) void k_sel_merge(
    const float* __restrict__ scores, const float4* __restrict__ boxes,
    const u64* __restrict__ arr,
    float* __restrict__ sb, float4* __restrict__ bbs, float* __restrict__ areas)
{
    const int img = blockIdx.y;
    const int t = blockIdx.x * 1024 + threadIdx.x;
    if (t >= PRE) return;
    const u64* A = arr + (size_t)img * NPAD;
    const u64* B = A + SHALF;
    int lo = (t > SHALF) ? (t - SHALF) : 0;
    int hi = (t < SHALF) ? t : SHALF;
    while (lo < hi) {
        int mid = (lo + hi) >> 1;          // mid in [lo,hi) -> A[mid], B[t-1-mid] in range
        if (A[mid] > B[t - 1 - mid]) lo = mid + 1; else hi = mid;
    }
    const int i = lo, j = t - lo;
    u64 va = (i < SHALF) ? A[i] : 0ull;
    u64 vb = (j < SHALF) ? B[j] : 0ull;
    u64 v = (va > vb) ? va : vb;
    u32 e = ~(u32)v;
    const float* sc = scores + (size_t)img * NA;
    float s = sc[e];
    float4 bx = boxes[(size_t)img * NA + e];
    sb[img * PRE + t] = s;
    bbs[img * PRE + t] = bx;
    areas[img * PRE + t] = (bx.z - bx.x) * (bx.w - bx.y);
}

// ---------------- kernel: IoU suppression bitmask (upper-triangular tiles) -------
__global__ __launch_bounds__(256) void k_mask(
    const float4* __restrict__ bbs, const float* __restrict__ areas,
    u64* __restrict__ mask)
{
    int img = blockIdx.z, iT = blockIdx.x, jT = blockIdx.y;
    if (jT * 256 + 255 <= iT * 64) return;
    int tid = threadIdx.x;
    __shared__ float4 jb[256];
    __shared__ float ja[256];
    int jj = jT * 256 + tid;
    jb[tid] = (jj < PRE) ? bbs[(size_t)img * PRE + jj] : make_float4(0, 0, 0, 0);
    ja[tid] = (jj < PRE) ? areas[img * PRE + jj] : 0.f;
    __syncthreads();
    int i = iT * 64 + (tid & 63);
    int jw = jT * 4 + (tid >> 6);
    if (i >= PRE) return;
    float4 bi = bbs[(size_t)img * PRE + i];
    float ai = areas[img * PRE + i];
    int j0 = (tid >> 6) * 64;
    u64 m = 0;
#pragma unroll 4
    for (int b = 0; b < 64; ++b) {
        int j = jw * 64 + b;
        if (j >= PRE) break;
        if (j > i) {
            float4 bj = jb[j0 + b];
            float xx1 = fmaxf(bi.x, bj.x), yy1 = fmaxf(bi.y, bj.y);
            float xx2 = fminf(bi.z, bj.z), yy2 = fminf(bi.w, bj.w);
            float iw = fmaxf(xx2 - xx1, 0.f), ih2 = fmaxf(yy2 - yy1, 0.f);
            float inter = iw * ih2;
            float iou = inter / (ai + ja[j0 + b] - inter + 1e-9f);
            if (iou > 0.7f) m |= (1ull << b);
        }
    }
    mask[((size_t)img * PRE + i) * MWORDS + jw] = m;
}

// ---------------- kernel: NMS scan, on-demand suppression gather -----------------
__global__ __launch_bounds__(256) void k_scan(
    const float* __restrict__ sb, const float4* __restrict__ bbs,
    const u64* __restrict__ mask, float* __restrict__ out2)
{
    const int img = blockIdx.x;
    const int tid = threadIdx.x;
    const int lane = tid & 63, wv = tid >> 6;   // 4 waves
    __shared__ u64 alive[94];
    __shared__ int list[POST];
    __shared__ int s_n;
    __shared__ u64 wred[4];

    for (int j0 = 0; j0 < 94 * 64; j0 += 256) {
        int j = j0 + tid;
        bool al = (j < PRE) && isfinite(sb[(size_t)img * PRE + j]);
        u64 bal = __ballot(al);
        if (lane == 0) alive[(j0 >> 6) + wv] = bal;
    }
    if (tid == 0) s_n = 0;
    __syncthreads();

    const u64* mimg = mask + (size_t)img * PRE * MWORDS;
    for (int w = 0; w < 94; ++w) {
        int n = s_n;
        if (n >= POST) break;
        u64 myrow = 0;
        if (wv == 0) myrow = mimg[(size_t)(w * 64 + lane) * MWORDS + w];
        u64 loc = 0;
        for (int t = tid; t < n; t += 256)
            loc |= mimg[(size_t)list[t] * MWORDS + w];
#pragma unroll
        for (int off = 32; off > 0; off >>= 1)
            loc |= __shfl_down(loc, off);
        if (lane == 0) wred[wv] = loc;
        __syncthreads();
        if (wv == 0) {
            u64 supp = wred[0] | wred[1] | wred[2] | wred[3];
            u64 cur = alive[w] & ~supp;
            u64 keptw = 0;
            while (cur) {
                int b = __builtin_ctzll(cur);
                keptw |= 1ull << b;
                u64 row = __shfl(myrow, b);
                u64 hi = (b >= 63) ? 0ull : (~0ull << (b + 1));
                cur &= ~row & hi;
            }
            if (lane == 0) {
                int nn = n;
                u64 bits = keptw;
                while (bits && nn < POST) {
                    int bb = __builtin_ctzll(bits);
                    bits &= bits - 1;
                    list[nn++] = w * 64 + bb;
                }
                s_n = nn;
            }
        }
        __syncthreads();
    }
    __syncthreads();
    int n = s_n;
    for (int e = tid; e < POST; e += 256) {
        float4 bx = (e < n) ? bbs[(size_t)img * PRE + list[e]] : make_float4(0, 0, 0, 0);
        *(float4*)&out2[((size_t)img * POST + e) * 4] = bx;
    }
}

extern "C" void kernel_launch(void* const* d_in, const int* in_sizes, int n_in,
                              void* d_out, int out_size, void* d_ws, size_t ws_size,
                              hipStream_t stream)
{
    const float* x     = (const float*)d_in[0];
    const float* w1    = (const float*)d_in[1];
    const float* b1    = (const float*)d_in[2];
    const float* sw    = (const float*)d_in[3];
    const float* sbias = (const float*)d_in[4];
    const float* lw    = (const float*)d_in[5];
    const float* lb    = (const float*)d_in[6];
    const int*   imh   = (const int*)d_in[7];
    const int*   imw   = (const int*)d_in[8];
    float* out = (float*)d_out;
    char* ws = (char*)d_ws;

    _Float16* wh2W = (_Float16*)(ws + 0);
    _Float16* wl2W = (_Float16*)(ws + 65536);
    _Float16* whW  = (_Float16*)(ws + 131072);
    _Float16* wlW  = (_Float16*)(ws + 4849664);
    _Float16* xhW  = (_Float16*)(ws + 9568256);
    _Float16* xlW  = (_Float16*)(ws + 25133056);
    float*    boxesW  = (float*)(ws + 17350656);
    float*    scoresW = (float*)(ws + 21728256);
    float*    sbW     = (float*)(ws + 22822656);
    float*    bbsW    = (float*)(ws + 23014656);
    float*    areasW  = (float*)(ws + 23782656);
    _Float16* fhW  = (_Float16*)(ws + 40697856);
    _Float16* flW  = (_Float16*)(ws + 71827456);
    u64*      maskW   = (u64*)(ws + 40697856);
    u32*      ghistW  = (u32*)(ws + 109581056);
    u32*      gccntW  = (u32*)(ws + 109589248);
    u32*      gprefW  = (u32*)(ws + 109589280);
    u32*      gremW   = (u32*)(ws + 109589312);
    u64*      arrW    = (u64*)(ws + 109597440);

    float* out0 = out;            // rpn_locs   (8,34200,4)
    float* out1 = out + 1094400;  // rpn_scores (8,34200,2)
    float* out2 = out + 1641600;  // rois       (2400,4)
    float* out3 = out + 1651200;  // anchors    (34200,4)

    // select control state lives outside every overlay -> safe to zero up front
    hipMemsetAsync(ws + 109581056, 0, 8224, stream);

    hipLaunchKernelGGL(k_split_w, dim3(512), dim3(256), 0, stream, w1, whW, wlW);
    hipLaunchKernelGGL(k_split_w2, dim3(64), dim3(512), 0, stream, lw, sw, wh2W, wl2W);
    for (int b = 0; b < 2; ++b) {
        hipLaunchKernelGGL(k_split_x, dim3(119, 16, 4), dim3(32, 8), 0, stream,
                           x + (size_t)b * 4 * CC * PP, xhW, xlW);
        hipLaunchKernelGGL(k_conv, dim3(480), dim3(256), 0, stream,
                           xhW, xlW, whW, wlW, b1, fhW, flW, b * 4);
    }
    hipLaunchKernelGGL(k_hgemm_post, dim3(60, NB), dim3(256), 0, stream,
                       fhW, flW, wh2W, wl2W, lb, sbias, imh, imw,
                       out0, out1, boxesW, scoresW, out3);
    for (int pass = 0; pass < 4; ++pass) {
        int sh = 24 - 8 * pass;
        hipLaunchKernelGGL(k_sel_hist, dim3(8, NB), dim3(256), 0, stream,
                           scoresW, ghistW, gprefW, sh, pass);
        hipLaunchKernelGGL(k_sel_scan, dim3(NB), dim3(256), 0, stream,
                           ghistW, gprefW, gremW, sh, pass);
    }
    hipLaunchKernelGGL(k_sel_collect, dim3(8, NB), dim3(256), 0, stream,
                       scoresW, gprefW, gccntW, arrW);
    hipLaunchKernelGGL(k_sel_sort2, dim3(2, NB), dim3(1024), 0, stream,
                       arrW, gccntW);
    hipLaunchKernelGGL(k_sel_merge, dim3((PRE + 1023) / 1024, NB), dim3(1024), 0, stream,
                       scoresW, (const float4*)boxesW, arrW,
                       sbW, (float4*)bbsW, areasW);
    hipLaunchKernelGGL(k_mask, dim3(94, 24, NB), dim3(256), 0, stream,
                       (const float4*)bbsW, areasW, maskW);
    hipLaunchKernelGGL(k_scan, dim3(NB), dim3(256), 0, stream,
                       sbW, (const float4*)bbsW, maskW, out2);
}

// Round 11
// 822.019 us; speedup vs baseline: 4.7807x; 1.0508x over previous
//
#include <hip/hip_runtime.h>
#include <stdint.h>
#include <math.h>

typedef unsigned long long u64;
typedef unsigned int u32;
typedef _Float16 half8 __attribute__((ext_vector_type(8)));
typedef float f32x4 __attribute__((ext_vector_type(4)));

#define CC   512
#define HH   50
#define WW2  76
#define PP   3800      // HH*WW2
#define NB   8
#define NA   34200     // PP*9
#define PRE  6000
#define POST 300
#define NPAD 8192      // candidate buffer size per image
#define SHALF 4096     // per-block bitonic sort size (NPAD/2)
#define SCHUNK 1069    // float4-chunks per select block (8 blocks x 1069 >= 8550)

// ---------------- workspace layout (bytes) ----------------
// wh2   @ 0            65,536      (64 x 512 f16)  [head weights hi]
// wl2   @ 65,536       65,536
// whF   @ 131,072      4,718,592   (frag-major conv weights hi: [g][kk][lane][8])
// wlF   @ 4,849,664    4,718,592
// xh    @ 9,568,256    15,564,800  (4 img * 3800 * 512 f16, per-batch)
// xl    @ 25,133,056   15,564,800
// --- after conv, xh/xl dead; overlay: ---
// boxes @ 17,350,656   4,377,600
// scores@ 21,728,256   1,094,400
// sb    @ 22,822,656     192,000
// bbs   @ 23,014,656     768,000
// areas @ 23,782,656     192,000
// fh    @ 40,697,856   31,129,600
// fl    @ 71,827,456   31,129,600
// selst @ 109,581,056     16,384   (ghist 8192 | gccnt | gpref | grem | gdone) - outside ALL overlays
// arr   @ 109,597,440    524,288   (NB x 8192 u64)
// peak ~110.1 MB (<= 115.7 MB proven safe)
// (mask buffer removed: IoU fused into k_scan)

__device__ __forceinline__ u32 skey(float f) {
    u32 u = __float_as_uint(f);
    return (u & 0x80000000u) ? ~u : (u | 0x80000000u);
}

__device__ __forceinline__ float4 anchor_at(int p, int a) {
    const float rv[3] = {0.5f, 1.0f, 2.0f};
    const float sv[3] = {8.0f, 16.0f, 32.0f};
    int ri = a / 3, si = a % 3;
    float s16 = 16.0f * sv[si];
    float hh = s16 * sqrtf(rv[ri]);
    float ww = s16 * sqrtf(1.0f / rv[ri]);
    float bx1 = 8.0f - 0.5f * ww, by1 = 8.0f - 0.5f * hh;
    float bx2 = 8.0f + 0.5f * ww, by2 = 8.0f + 0.5f * hh;
    float sx = (float)((p % WW2) * 16);
    float sy = (float)((p / WW2) * 16);
    return make_float4(sx + bx1, sy + by1, sx + bx2, sy + by2);
}

// LDS slot swizzle for A staging: octet j of row m
__device__ __forceinline__ int lds_slot(int m, int j) {
    return (((m >> 4) * 64) + ((m & 15) ^ ((4 * (j & 1)) | (8 * (j >> 1)))) + (j << 4)) << 3;
}

// ---------------- kernel: split x into f16 hi/lo, transposed [p][c] --------------
// grid (119, 16, 4), block (32,8)
__global__ void k_split_x(const float* __restrict__ x, _Float16* __restrict__ xh,
                          _Float16* __restrict__ xl) {
    __shared__ float S[32][33];
    int zim = blockIdx.z;
    int p0 = blockIdx.x * 32, c0 = blockIdx.y * 32;
    int tx = threadIdx.x, ty0 = threadIdx.y;
    const float* xi = x + (size_t)zim * CC * PP;
#pragma unroll
    for (int yy = 0; yy < 32; yy += 8) {
        int cty = c0 + ty0 + yy, ptx = p0 + tx;
        S[ty0 + yy][tx] = (ptx < PP) ? xi[(size_t)cty * PP + ptx] : 0.f;
    }
    __syncthreads();
#pragma unroll
    for (int yy = 0; yy < 32; yy += 8) {
        int p = p0 + ty0 + yy;
        if (p < PP) {
            float v = S[tx][ty0 + yy];
            _Float16 h = (_Float16)v;
            float r = v - (float)h;
            size_t o = (size_t)(zim * PP + p) * 512 + c0 + tx;
            xh[o] = h;
            xl[o] = (_Float16)(r * 2048.0f);
        }
    }
}

// ---------------- kernel: split conv1 + head weights (fused) ---------------------
// blocks 0..511: conv weights -> frag-major hi/lo (original k_split_w).
// blocks 512..575: head weights row (block-512) -> [64][512] hi/lo (k_split_w2).
__global__ void k_split_wall(const float* __restrict__ w, _Float16* __restrict__ wh,
                             _Float16* __restrict__ wl,
                             const float* __restrict__ lw, const float* __restrict__ sw,
                             _Float16* __restrict__ wh2, _Float16* __restrict__ wl2) {
    if (blockIdx.x >= 512) {
        int row = blockIdx.x - 512;
        for (int k = threadIdx.x; k < 512; k += 256) {
            float v = (row < 36) ? lw[row * 512 + k]
                                 : (row < 54 ? sw[(row - 36) * 512 + k] : 0.f);
            _Float16 h = (_Float16)v;
            float r = v - (float)h;
            wh2[row * 512 + k] = h;
            wl2[row * 512 + k] = (_Float16)(r * 2048.0f);
        }
        return;
    }
    __shared__ float S[4608];
    int co = blockIdx.x;
    for (int t = threadIdx.x; t < 4608; t += 256) S[t] = w[(size_t)co * 4608 + t];
    __syncthreads();
    int g = co >> 4, nlo = co & 15;
    for (int e = threadIdx.x; e < 4608; e += 256) {
        int cc = e / 9, idx = e - cc * 9;          // e enumerates (ci, idx)
        float v = S[cc * 9 + idx];
        _Float16 h = (_Float16)v;
        float r = v - (float)h;
        int kk = (cc >> 5) * 9 + idx;
        int lane = ((cc >> 3) & 3) * 16 + nlo;
        int j = cc & 7;
        size_t d = (((size_t)g * 144 + kk) * 64 + lane) * 8 + j;
        wh[d] = h;
        wl[d] = (_Float16)(r * 2048.0f);
    }
}

// ---------------- kernel: 3x3 conv via split-f16 MFMA implicit GEMM --------------
// 1-D grid 480 (XCD-pinned), block 256 (4 waves, 2x2), BM=BN=128, BK=32.
// PROVEN 231us form.  Register-file-bound at 2 blocks/CU (128 VGPR + 128 AGPR acc).
// Final verdict: do NOT restructure (round-6 spill 7.7x; round-9 big-LDS pipeline
// killed the container).  This is the 2-phase structure's ceiling (~941 TF eff).
__global__ __launch_bounds__(256, 2) void k_conv(
    const _Float16* __restrict__ xh, const _Float16* __restrict__ xl,
    const _Float16* __restrict__ whF, const _Float16* __restrict__ wlF,
    const float* __restrict__ bias, _Float16* __restrict__ fh,
    _Float16* __restrict__ fl, int imgbase)
{
    __shared__ _Float16 lds[2 * 8192];
    const int tid = threadIdx.x;
    const int L = blockIdx.x;
    const int X = L & 7, q = L >> 3;          // q in 0..59
    const int nt = X & 3;
    const int zim = (X >> 2) * 2 + (q >= 30 ? 1 : 0);
    const int mt = q - (q >= 30 ? 30 : 0);
    const int m0 = mt * 128, n0 = nt * 128;
    const _Float16* xhi = xh + (size_t)zim * CC * PP;
    const _Float16* xlo = xl + (size_t)zim * CC * PP;

    const int mA0 = tid >> 2, jA0 = tid & 3;
    const int mA1 = 64 + (tid >> 2);

    f32x4 acc[4][4], acc2[4][4];
#pragma unroll
    for (int i = 0; i < 4; ++i)
#pragma unroll
        for (int j = 0; j < 4; ++j) {
            acc[i][j] = f32x4{0.f, 0.f, 0.f, 0.f};
            acc2[i][j] = f32x4{0.f, 0.f, 0.f, 0.f};
        }

    uint4 pa0h, pa0l, pa1h, pa1l;

    auto ld_a = [&](int m, int idx, int c0, uint4& vh, uint4& vl) {
        int dy = idx / 3 - 1, dx = idx % 3 - 1;
        int p = m0 + m;
        int px = p % 76, py = p / 76;
        bool av = (p < PP) && ((unsigned)(py + dy) < 50u) && ((unsigned)(px + dx) < 76u);
        if (av) {
            size_t off = (size_t)(p + dy * 76 + dx) * 512 + c0 + jA0 * 8;
            vh = *(const uint4*)(xhi + off);
            vl = *(const uint4*)(xlo + off);
        } else {
            vh = make_uint4(0, 0, 0, 0);
            vl = make_uint4(0, 0, 0, 0);
        }
    };
    auto stage_load = [&](int kk) {
        int c9 = kk / 9;                   // c-chunk outer, idx inner
        int idx = kk - c9 * 9;
        int c0 = c9 << 5;
        ld_a(mA0, idx, c0, pa0h, pa0l);
        ld_a(mA1, idx, c0, pa1h, pa1l);
    };
    const int sl0 = lds_slot(mA0, jA0);
    const int sl1 = lds_slot(mA1, jA0);
    auto stage_write = [&](int buf) {
        _Float16* Lp = lds + buf * 8192;
        *(uint4*)(Lp + sl0)        = pa0h;
        *(uint4*)(Lp + 4096 + sl0) = pa0l;
        *(uint4*)(Lp + sl1)        = pa1h;
        *(uint4*)(Lp + 4096 + sl1) = pa1l;
    };

    const int lane = tid & 63, wave = tid >> 6;
    const int wm = wave & 1, wn = wave >> 1;
    const int jr = lane >> 4;
    const int rd_off = (((lane & 15) ^ ((4 * (jr & 1)) | (8 * (jr >> 1)))) + (jr << 4)) << 3;
    const int g0 = nt * 8 + wn * 4;                 // base B frag index
    const size_t lane8 = (size_t)lane * 8;

    half8 b0h[4], b0l[4], b1h[4], b1l[4];
    auto load_b = [&](int kk, half8* bh_, half8* bl_) {
#pragma unroll
        for (int ni = 0; ni < 4; ++ni) {
            size_t off = (((size_t)(g0 + ni) * 144 + kk) * 64) * 8 + lane8;
            bh_[ni] = *(const half8*)(whF + off);
            bl_[ni] = *(const half8*)(wlF + off);
        }
    };

    auto compute = [&](int buf, const half8* bh, const half8* bl) {
        const _Float16* Lp = lds + buf * 8192;
        half8 ah[4], al[4];
#pragma unroll
        for (int mi = 0; mi < 4; ++mi) {
            int slot = (((wm * 4 + mi) * 64) << 3) + rd_off;
            ah[mi] = *(const half8*)(Lp + slot);
            al[mi] = *(const half8*)(Lp + 4096 + slot);
        }
#pragma unroll
        for (int ni = 0; ni < 4; ++ni) {
#pragma unroll
            for (int mi = 0; mi < 4; ++mi) {
                acc[mi][ni]  = __builtin_amdgcn_mfma_f32_16x16x32_f16(ah[mi], bh[ni], acc[mi][ni], 0, 0, 0);
                acc2[mi][ni] = __builtin_amdgcn_mfma_f32_16x16x32_f16(ah[mi], bl[ni], acc2[mi][ni], 0, 0, 0);
                acc2[mi][ni] = __builtin_amdgcn_mfma_f32_16x16x32_f16(al[mi], bh[ni], acc2[mi][ni], 0, 0, 0);
            }
        }
    };

    stage_load(0);
    stage_write(0);
    load_b(0, b0h, b0l);
    __syncthreads();
    // K loop unrolled by 2: explicit register ping-pong for B (no copies)
    for (int kk = 0; kk < 144; kk += 2) {
        // chunk kk (A buf = 0)
        stage_load(kk + 1);
        load_b(kk + 1, b1h, b1l);
        compute(0, b0h, b0l);
        stage_write(1);
        __syncthreads();
        // chunk kk+1 (A buf = 1)
        if (kk + 2 < 144) {
            stage_load(kk + 2);
            load_b(kk + 2, b0h, b0l);
        }
        compute(1, b1h, b1l);
        if (kk + 2 < 144) stage_write(0);
        __syncthreads();
    }

    const int qq = lane >> 4, cl = lane & 15;
    const size_t rowbase = (size_t)(imgbase + zim) * PP;
#pragma unroll
    for (int ni = 0; ni < 4; ++ni) {
        int n = n0 + (wn * 4 + ni) * 16 + cl;
        float bs = bias[n];
#pragma unroll
        for (int mi = 0; mi < 4; ++mi) {
            int mb = m0 + (wm * 4 + mi) * 16 + qq * 4;
            if (mb < PP) {
#pragma unroll
                for (int r = 0; r < 4; ++r) {
                    float v = fmaxf(acc[mi][ni][r] + acc2[mi][ni][r] * (1.f / 2048.f) + bs, 0.f);
                    _Float16 h = (_Float16)v;
                    float rr = v - (float)h;
                    size_t o = (rowbase + mb + r) * 512 + n;
                    fh[o] = h;
                    fl[o] = (_Float16)(rr * 2048.0f);
                }
            }
        }
    }
}

// ---------------- kernel: head GEMM + fused decode (k_post folded in) ------------
__global__ __launch_bounds__(256) void k_hgemm_post(
    const _Float16* __restrict__ fh, const _Float16* __restrict__ fl,
    const _Float16* __restrict__ wh2, const _Float16* __restrict__ wl2,
    const float* __restrict__ lb, const float* __restrict__ sbias,
    const int* __restrict__ imh_p, const int* __restrict__ imw_p,
    float* __restrict__ out0, float* __restrict__ out1,
    float* __restrict__ boxes, float* __restrict__ scores,
    float* __restrict__ out3)
{
    const int img = blockIdx.y;
    const int p0 = blockIdx.x * 64;
    const int wave = threadIdx.x >> 6, lane = threadIdx.x & 63;
    const int q8 = (lane >> 4) * 8;
    int arow = img * PP + p0 + wave * 16 + (lane & 15);
    if (arow >= NB * PP) arow = NB * PP - 1;
    const _Float16* fhp = fh + (size_t)arow * 512 + q8;
    const _Float16* flp = fl + (size_t)arow * 512 + q8;
    const _Float16* bhp = wh2 + (size_t)(lane & 15) * 512 + q8;
    const _Float16* blp = wl2 + (size_t)(lane & 15) * 512 + q8;

    f32x4 acc[4], acc2[4];
#pragma unroll
    for (int j = 0; j < 4; ++j) {
        acc[j] = f32x4{0.f, 0.f, 0.f, 0.f};
        acc2[j] = f32x4{0.f, 0.f, 0.f, 0.f};
    }

#pragma unroll 4
    for (int k0 = 0; k0 < 512; k0 += 32) {
        half8 ah = *(const half8*)(fhp + k0);
        half8 al = *(const half8*)(flp + k0);
#pragma unroll
        for (int nf = 0; nf < 4; ++nf) {
            half8 bh = *(const half8*)(bhp + (size_t)nf * 16 * 512 + k0);
            half8 bl = *(const half8*)(blp + (size_t)nf * 16 * 512 + k0);
            acc[nf]  = __builtin_amdgcn_mfma_f32_16x16x32_f16(ah, bh, acc[nf], 0, 0, 0);
            acc2[nf] = __builtin_amdgcn_mfma_f32_16x16x32_f16(ah, bl, acc2[nf], 0, 0, 0);
            acc2[nf] = __builtin_amdgcn_mfma_f32_16x16x32_f16(al, bh, acc2[nf], 0, 0, 0);
        }
    }

    // stage the 64x64 O tile to LDS
    __shared__ float Ls[64][68];
    const int q = lane >> 4, cl = lane & 15;
#pragma unroll
    for (int nf = 0; nf < 4; ++nf) {
        int n = nf * 16 + cl;
        float bs = (n < 36) ? lb[n] : (n < 54 ? sbias[n - 36] : 0.f);
#pragma unroll
        for (int r = 0; r < 4; ++r) {
            int ml = wave * 16 + q * 4 + r;
            Ls[ml][n] = acc[nf][r] + acc2[nf][r] * (1.f / 2048.f) + bs;
        }
    }
    __syncthreads();

    // decode: 64 rows x 9 anchors = 576 tasks over 256 threads
    const float fimh = (float)(*imh_p), fimw = (float)(*imw_p);
    for (int task = threadIdx.x; task < 576; task += 256) {
        int pl = task / 9, a = task - pl * 9;
        int p = p0 + pl;
        if (p >= PP) continue;
        float4 loc = *(const float4*)&Ls[pl][a * 4];
        float2 sc = make_float2(Ls[pl][36 + a * 2], Ls[pl][36 + a * 2 + 1]);
        size_t ai = (size_t)img * NA + (size_t)p * 9 + a;
        *(float4*)&out0[ai * 4] = loc;
        *(float2*)&out1[ai * 2] = sc;
        float mx = fmaxf(sc.x, sc.y);
        float e0 = expf(sc.x - mx), e1 = expf(sc.y - mx);
        float fg = e1 / (e0 + e1);
        float4 an = anchor_at(p, a);
        if (img == 0) ((float4*)out3)[p * 9 + a] = an;
        float aw = an.z - an.x, ah = an.w - an.y;
        float ax = an.x + 0.5f * aw, ay = an.y + 0.5f * ah;
        float cx = loc.x * aw + ax;
        float cy = loc.y * ah + ay;
        float wb = expf(loc.z) * aw, hb = expf(loc.w) * ah;
        float x1 = cx - 0.5f * wb, y1 = cy - 0.5f * hb;
        float x2 = cx + 0.5f * wb, y2 = cy + 0.5f * hb;
        x1 = fminf(fmaxf(x1, 0.f), fimw);
        x2 = fminf(fmaxf(x2, 0.f), fimw);
        y1 = fminf(fmaxf(y1, 0.f), fimh);
        y2 = fminf(fmaxf(y2, 0.f), fimh);
        bool valid = ((x2 - x1) >= 16.0f) && ((y2 - y1) >= 16.0f);
        ((float4*)boxes)[ai] = make_float4(x1, y1, x2, y2);
        scores[ai] = valid ? fg : -INFINITY;
    }
}

// ================= selection pipeline ============================================

// ---- fused histogram + scan: per-wave LDS hist -> global atomics; the LAST
// block per image (threadfence+ticket) runs the 256-bin suffix-scan inline,
// reading ghist via atomic-RMW (device-scope, XCD-coherent), picks the digit,
// updates gpref/grem, and re-zeroes ghist for the next pass. --------------------
__global__ __launch_bounds__(256) void k_sel_histscan(
    const float* __restrict__ scores, u32* __restrict__ ghist,
    u32* __restrict__ gpref, u32* __restrict__ grem, u32* __restrict__ gdone,
    int sh, int pass)
{
    __shared__ u32 wh[4][256];
    __shared__ u32 A[256];
    __shared__ int s_last, s_d;
    const int img = blockIdx.y, blk = blockIdx.x;
    const int tid = threadIdx.x, wv = tid >> 6;
#pragma unroll
    for (int w = 0; w < 4; ++w) wh[w][tid] = 0;
    __syncthreads();
    const u32 pmask = (pass == 0) ? 0u : (0xFFFFFFFFu << (sh + 8));
    const u32 pref = (pass == 0) ? 0u : gpref[img];
    const float4* sc4 = (const float4*)(scores + (size_t)img * NA);
    const int e40 = blk * SCHUNK;
    const int e41 = min(e40 + SCHUNK, NA / 4);
    for (int e4 = e40 + tid; e4 < e41; e4 += 256) {
        float4 s4 = sc4[e4];
        u32 kv[4] = {skey(s4.x), skey(s4.y), skey(s4.z), skey(s4.w)};
#pragma unroll
        for (int v = 0; v < 4; ++v)
            if ((kv[v] & pmask) == pref) atomicAdd(&wh[wv][(kv[v] >> sh) & 255u], 1u);
    }
    __syncthreads();
    u32 s = wh[0][tid] + wh[1][tid] + wh[2][tid] + wh[3][tid];
    if (s) atomicAdd(&ghist[img * 256 + tid], s);
    __threadfence();
    __syncthreads();
    if (tid == 0) s_last = (atomicAdd(&gdone[pass * 8 + img], 1u) == 7u) ? 1 : 0;
    __syncthreads();
    if (!s_last) return;
    // last block for this image: inline scan
    u32 h = atomicAdd(&ghist[img * 256 + tid], 0u);   // coherent read
    A[tid] = h;
    if (tid == 0) s_d = 0;
    __syncthreads();
    for (int off = 1; off < 256; off <<= 1) {
        u32 v = A[tid] + ((tid + off < 256) ? A[tid + off] : 0u);
        __syncthreads();
        A[tid] = v;
        __syncthreads();
    }
    const u32 rem = (pass == 0) ? (u32)PRE : grem[img];
    if (A[tid] >= rem) atomicMax(&s_d, tid);
    __syncthreads();
    if (tid == 0) {
        int d = s_d;
        u32 snext = (d < 255) ? A[d + 1] : 0u;
        u32 pv = (pass == 0) ? 0u : gpref[img];
        gpref[img] = pv | ((u32)d << sh);
        grem[img] = rem - snext;
    }
    ghist[img * 256 + tid] = 0;    // visible to next pass via kernel boundary
}

// ---- collect: block-local LDS compaction, one global atomic per block -----------
__global__ __launch_bounds__(256) void k_sel_collect(
    const float* __restrict__ scores, const u32* __restrict__ gpref,
    u32* __restrict__ gccnt, u64* __restrict__ arr)
{
    __shared__ u64 lst[4288];
    __shared__ u32 s_c, s_base;
    const int img = blockIdx.y, blk = blockIdx.x;
    const int tid = threadIdx.x, lane = tid & 63;
    if (tid == 0) s_c = 0;
    __syncthreads();
    const u32 T = gpref[img];
    const float4* sc4 = (const float4*)(scores + (size_t)img * NA);
    const int e40 = blk * SCHUNK;
    const int e41 = min(e40 + SCHUNK, NA / 4);
    for (int e4 = e40 + tid; e4 < e41; e4 += 256) {
        float4 s4 = sc4[e4];
        u32 ks[4] = {skey(s4.x), skey(s4.y), skey(s4.z), skey(s4.w)};
#pragma unroll
        for (int v = 0; v < 4; ++v) {
            bool take = ks[v] >= T;
            u64 bal = __ballot(take);
            if (bal) {
                int leader = __builtin_ctzll(bal);
                u32 base = 0;
                if (lane == leader) base = atomicAdd(&s_c, (u32)__popcll(bal));
                base = (u32)__shfl((int)base, leader);
                if (take)
                    lst[base + (u32)__popcll(bal & ((1ull << lane) - 1ull))] =
                        ((u64)ks[v] << 32) | (u64)(~(u32)(e4 * 4 + v));
            }
        }
    }
    __syncthreads();
    if (tid == 0) s_base = atomicAdd(&gccnt[img], s_c);
    __syncthreads();
    const u32 base = s_base, c = s_c;
    u64* ar = arr + (size_t)img * NPAD;
    for (u32 t = tid; t < c; t += 256) {
        u32 pos = base + t;
        if (pos < NPAD) ar[pos] = lst[t];
    }
}

// ---- sub-sort: each block bitonic-sorts one 4096-half descending, in place ------
__global__ __launch_bounds__(1024) void k_sel_sort2(
    u64* __restrict__ arr, const u32* __restrict__ gccnt)
{
    __shared__ u64 a[SHALF];
    const int img = blockIdx.y, half = blockIdx.x;
    const int tid = threadIdx.x;
    u32 n = gccnt[img]; if (n > NPAD) n = NPAD;
    u64* ar = arr + (size_t)img * NPAD + (size_t)half * SHALF;
    const int base = half * SHALF;
    for (int t = tid; t < SHALF; t += 1024)
        a[t] = ((u32)(base + t) < n) ? ar[t] : 0ull;
    for (u32 size = 2; size <= SHALF; size <<= 1) {
        for (u32 stride = size >> 1; stride > 0; stride >>= 1) {
            __syncthreads();
            for (u32 t2 = tid; t2 < SHALF / 2; t2 += 1024) {
                u32 i = 2 * t2 - (t2 & (stride - 1));
                u32 j = i + stride;
                u64 x = a[i], y = a[j];
                bool desc = ((i & size) == 0);
                if (desc ? (x < y) : (x > y)) { a[i] = y; a[j] = x; }
            }
        }
    }
    __syncthreads();
    for (int t = tid; t < SHALF; t += 1024) ar[t] = a[t];
}

// ---- merge: rank-t output via merge-path co-rank over the two sorted halves -----
__global__ __launch_bounds__(1024) void k_sel_merge(
    const float* __restrict__ scores, const float4* __restrict__ boxes,
    const u64* __restrict__ arr,
    float* __restrict__ sb, float4* __restrict__ bbs, float* __restrict__ areas)
{
    const int img = blockIdx.y;
    const int t = blockIdx.x * 1024 + threadIdx.x;
    if (t >= PRE) return;
    const u64* A = arr + (size_t)img * NPAD;
    const u64* B = A + SHALF;
    int lo = (t > SHALF) ? (t - SHALF) : 0;
    int hi = (t < SHALF) ? t : SHALF;
    while (lo < hi) {
        int mid = (lo + hi) >> 1;
        if (A[mid] > B[t - 1 - mid]) lo = mid + 1; else hi = mid;
    }
    const int i = lo, j = t - lo;
    u64 va = (i < SHALF) ? A[i] : 0ull;
    u64 vb = (j < SHALF) ? B[j] : 0ull;
    u64 v = (va > vb) ? va : vb;
    u32 e = ~(u32)v;
    const float* sc = scores + (size_t)img * NA;
    float s = sc[e];
    float4 bx = boxes[(size_t)img * NA + e];
    sb[img * PRE + t] = s;
    bbs[img * PRE + t] = bx;
    areas[img * PRE + t] = (bx.z - bx.x) * (bx.w - bx.y);
}

// ---------------- kernel: NMS scan with FUSED IoU (k_mask eliminated) ------------
// Per step w: (a) all 256 threads load word-w boxes + compute the 64x64 intra-word
// IoU rows 4-way-partitioned into rowp; (b) supp = OR over the kept list (boxes
// cached in LDS) of per-kept 64-bit IoU masks, block-reduced; (c) wave 0 runs the
// unchanged greedy diag bit-walk and appends kept boxes.  IoU expression is
// bit-identical to the old k_mask; greedy order identical to the proven scan.
__global__ __launch_bounds__(256) void k_scan(
    const float* __restrict__ sb, const float4* __restrict__ bbs,
    float* __restrict__ out2)
{
    const int img = blockIdx.x;
    const int tid = threadIdx.x;
    const int lane = tid & 63, wv = tid >> 6;   // 4 waves
    __shared__ u64 alive[94];
    __shared__ int list[POST];
    __shared__ float4 kb[POST];
    __shared__ float ka[POST];
    __shared__ float4 wb4[64];
    __shared__ float wa[64];
    __shared__ u64 rowp[4][64];
    __shared__ u64 wred[4];
    __shared__ int s_n;

    for (int j0 = 0; j0 < 94 * 64; j0 += 256) {
        int j = j0 + tid;
        bool al = (j < PRE) && isfinite(sb[(size_t)img * PRE + j]);
        u64 bal = __ballot(al);
        if (lane == 0) alive[(j0 >> 6) + wv] = bal;
    }
    if (tid == 0) s_n = 0;
    __syncthreads();

    for (int w = 0; w < 94; ++w) {
        int n = s_n;
        if (n >= POST) break;
        // load word-w boxes + areas into LDS
        if (tid < 64) {
            int j = w * 64 + tid;
            float4 b = (j < PRE) ? bbs[(size_t)img * PRE + j] : make_float4(0, 0, 0, 0);
            wb4[tid] = b;
            wa[tid] = (b.z - b.x) * (b.w - b.y);
        }
        __syncthreads();
        // intra-word IoU rows, 4-way partitioned: thread (l = tid&63, part = tid>>6)
        {
            int l = tid & 63, part = tid >> 6;
            float4 bl = wb4[l];
            float al_ = wa[l];
            u64 m = 0;
            int b0 = part * 16;
#pragma unroll 4
            for (int b = b0; b < b0 + 16; ++b) {
                float4 bj = wb4[b];
                float xx1 = fmaxf(bl.x, bj.x), yy1 = fmaxf(bl.y, bj.y);
                float xx2 = fminf(bl.z, bj.z), yy2 = fminf(bl.w, bj.w);
                float iw = fmaxf(xx2 - xx1, 0.f), ih2 = fmaxf(yy2 - yy1, 0.f);
                float inter = iw * ih2;
                float iou = inter / (al_ + wa[b] - inter + 1e-9f);
                if (iou > 0.7f) m |= (1ull << b);
            }
            rowp[part][l] = m;
        }
        // suppression of word w by previously-kept boxes (LDS-cached)
        u64 loc = 0;
        for (int t = tid; t < n; t += 256) {
            float4 kbx = kb[t];
            float kar = ka[t];
            u64 m = 0;
#pragma unroll 4
            for (int b = 0; b < 64; ++b) {
                float4 bj = wb4[b];
                float xx1 = fmaxf(kbx.x, bj.x), yy1 = fmaxf(kbx.y, bj.y);
                float xx2 = fminf(kbx.z, bj.z), yy2 = fminf(kbx.w, bj.w);
                float iw = fmaxf(xx2 - xx1, 0.f), ih2 = fmaxf(yy2 - yy1, 0.f);
                float inter = iw * ih2;
                float iou = inter / (kar + wa[b] - inter + 1e-9f);
                if (iou > 0.7f) m |= (1ull << b);
            }
            loc |= m;
        }
#pragma unroll
        for (int off = 32; off > 0; off >>= 1)
            loc |= __shfl_down(loc, off);
        if (lane == 0) wred[wv] = loc;
        __syncthreads();
        if (wv == 0) {
            u64 supp = wred[0] | wred[1] | wred[2] | wred[3];
            u64 myrow = rowp[0][lane] | rowp[1][lane] | rowp[2][lane] | rowp[3][lane];
            u64 cur = alive[w] & ~supp;
            u64 keptw = 0;
            while (cur) {
                int b = __builtin_ctzll(cur);
                keptw |= 1ull << b;
                u64 row = __shfl(myrow, b);
                u64 hi = (b >= 63) ? 0ull : (~0ull << (b + 1));
                cur &= ~row & hi;
            }
            if (lane == 0) {
                int nn = n;
                u64 bits = keptw;
                while (bits && nn < POST) {
                    int bb = __builtin_ctzll(bits);
                    bits &= bits - 1;
                    list[nn] = w * 64 + bb;
                    kb[nn] = wb4[bb];
                    ka[nn] = wa[bb];
                    ++nn;
                }
                s_n = nn;
            }
        }
        __syncthreads();
    }
    __syncthreads();
    int n = s_n;
    for (int e = tid; e < POST; e += 256) {
        float4 bx = (e < n) ? bbs[(size_t)img * PRE + list[e]] : make_float4(0, 0, 0, 0);
        *(float4*)&out2[((size_t)img * POST + e) * 4] = bx;
    }
}

extern "C" void kernel_launch(void* const* d_in, const int* in_sizes, int n_in,
                              void* d_out, int out_size, void* d_ws, size_t ws_size,
                              hipStream_t stream)
{
    const float* x     = (const float*)d_in[0];
    const float* w1    = (const float*)d_in[1];
    const float* b1    = (const float*)d_in[2];
    const float* sw    = (const float*)d_in[3];
    const float* sbias = (const float*)d_in[4];
    const float* lw    = (const float*)d_in[5];
    const float* lb    = (const float*)d_in[6];
    const int*   imh   = (const int*)d_in[7];
    const int*   imw   = (const int*)d_in[8];
    float* out = (float*)d_out;
    char* ws = (char*)d_ws;

    _Float16* wh2W = (_Float16*)(ws + 0);
    _Float16* wl2W = (_Float16*)(ws + 65536);
    _Float16* whW  = (_Float16*)(ws + 131072);
    _Float16* wlW  = (_Float16*)(ws + 4849664);
    _Float16* xhW  = (_Float16*)(ws + 9568256);
    _Float16* xlW  = (_Float16*)(ws + 25133056);
    float*    boxesW  = (float*)(ws + 17350656);
    float*    scoresW = (float*)(ws + 21728256);
    float*    sbW     = (float*)(ws + 22822656);
    float*    bbsW    = (float*)(ws + 23014656);
    float*    areasW  = (float*)(ws + 23782656);
    _Float16* fhW  = (_Float16*)(ws + 40697856);
    _Float16* flW  = (_Float16*)(ws + 71827456);
    u32*      ghistW  = (u32*)(ws + 109581056);
    u32*      gccntW  = (u32*)(ws + 109589248);
    u32*      gprefW  = (u32*)(ws + 109589280);
    u32*      gremW   = (u32*)(ws + 109589312);
    u32*      gdoneW  = (u32*)(ws + 109589344);
    u64*      arrW    = (u64*)(ws + 109597440);

    float* out0 = out;            // rpn_locs   (8,34200,4)
    float* out1 = out + 1094400;  // rpn_scores (8,34200,2)
    float* out2 = out + 1641600;  // rois       (2400,4)
    float* out3 = out + 1651200;  // anchors    (34200,4)

    // zero select control state (ghist + gccnt + gpref + grem + gdone);
    // lives outside every overlay -> safe to zero up front
    hipMemsetAsync(ws + 109581056, 0, 8416, stream);

    hipLaunchKernelGGL(k_split_wall, dim3(576), dim3(256), 0, stream,
                       w1, whW, wlW, lw, sw, wh2W, wl2W);
    for (int b = 0; b < 2; ++b) {
        hipLaunchKernelGGL(k_split_x, dim3(119, 16, 4), dim3(32, 8), 0, stream,
                           x + (size_t)b * 4 * CC * PP, xhW, xlW);
        hipLaunchKernelGGL(k_conv, dim3(480), dim3(256), 0, stream,
                           xhW, xlW, whW, wlW, b1, fhW, flW, b * 4);
    }
    hipLaunchKernelGGL(k_hgemm_post, dim3(60, NB), dim3(256), 0, stream,
                       fhW, flW, wh2W, wl2W, lb, sbias, imh, imw,
                       out0, out1, boxesW, scoresW, out3);
    for (int pass = 0; pass < 4; ++pass) {
        int sh = 24 - 8 * pass;
        hipLaunchKernelGGL(k_sel_histscan, dim3(8, NB), dim3(256), 0, stream,
                           scoresW, ghistW, gprefW, gremW, gdoneW, sh, pass);
    }
    hipLaunchKernelGGL(k_sel_collect, dim3(8, NB), dim3(256), 0, stream,
                       scoresW, gprefW, gccntW, arrW);
    hipLaunchKernelGGL(k_sel_sort2, dim3(2, NB), dim3(1024), 0, stream,
                       arrW, gccntW);
    hipLaunchKernelGGL(k_sel_merge, dim3((PRE + 1023) / 1024, NB), dim3(1024), 0, stream,
                       scoresW, (const float4*)boxesW, arrW,
                       sbW, (float4*)bbsW, areasW);
    hipLaunchKernelGGL(k_scan, dim3(NB), dim3(256), 0, stream,
                       sbW, (const float4*)bbsW, out2);
}